// Round 19
// baseline (503.750 us; speedup 1.0000x reference)
//
#include <hip/hip_runtime.h>
#include <stdint.h>

// Problem constants
#define BATCH   2048
#define DIM     768
#define FEAT    16384
#define KSEL    64
#define KB_SEL  (BATCH * KSEL)      // 131072 selected
#define N_TOT   (BATCH * FEAT)      // 33554432
#define NX4     (BATCH * DIM / 4)
#define NW4     (FEAT * DIM / 4)

// MFMA GEMM tiling
#define GBM 128
#define GBN 128
#define GBK 32
#define AROW   24
#define APLANE 3088

// Margin: Y(bf16 out of bf16 MFMA) vs f64 max err ~7e-3; 32768 ranks ~34e-3 band
#define MARGIN  32768
#define CCAP    229376
#define TIE_CAP 1024
#define LSTAGE  2048

// scalar slots
#define SL_T32    0
#define SL_NC     1
#define SL_DEF    2
#define SL_NTIE   3
#define SL_WIN    4
#define SL_S0     16

typedef __attribute__((ext_vector_type(8))) __bf16 bf16x8;
typedef __attribute__((ext_vector_type(4))) float  f32x4;
typedef unsigned long long u64;

__device__ __forceinline__ unsigned short bf16r(float v)
{
    unsigned u = __float_as_uint(v);
    u += 0x7FFFu + ((u >> 16) & 1u);
    return (unsigned short)(u >> 16);
}

__device__ __forceinline__ unsigned wave_append(unsigned* counter, bool pred)
{
    unsigned long long m = __ballot(pred);
    if (m == 0ull) return 0xFFFFFFFFu;
    const int lane = threadIdx.x & 63;
    const int leader = __ffsll((unsigned long long)m) - 1;
    unsigned base = 0;
    if (lane == leader) base = atomicAdd(counter, (unsigned)__popcll(m));
    base = __shfl(base, leader, 64);
    if (!pred) return 0xFFFFFFFFu;
    return base + (unsigned)__popcll(m & ((1ull << lane) - 1ull));
}

// ===========================================================================
// Pre-convert: xb = bf16(x - bdec), wb = bf16(Wenc), once
// ===========================================================================
__global__ __launch_bounds__(256) void sae15_prep(const float* __restrict__ x,
                                                  const float* __restrict__ Wenc,
                                                  const float* __restrict__ bdec,
                                                  unsigned short* __restrict__ xb,
                                                  unsigned short* __restrict__ wb)
{
    const int tot = NX4 + NW4;
    for (int i = blockIdx.x * 256 + threadIdx.x; i < tot; i += gridDim.x * 256) {
        if (i < NX4) {
            const int e = i * 4;
            const int d = e % DIM;
            float4 v  = *(const float4*)(x + e);
            float4 dv = *(const float4*)(bdec + d);
            uint2 p;
            p.x = (unsigned)bf16r(v.x - dv.x) | ((unsigned)bf16r(v.y - dv.y) << 16);
            p.y = (unsigned)bf16r(v.z - dv.z) | ((unsigned)bf16r(v.w - dv.w) << 16);
            *(uint2*)(xb + e) = p;
        } else {
            const int e = (i - NX4) * 4;
            float4 v = *(const float4*)(Wenc + e);
            uint2 p;
            p.x = (unsigned)bf16r(v.x) | ((unsigned)bf16r(v.y) << 16);
            p.y = (unsigned)bf16r(v.z) | ((unsigned)bf16r(v.w) << 16);
            *(uint2*)(wb + e) = p;
        }
    }
}

// ===========================================================================
// Encode GEMM — bf16 MFMA from pre-converted inputs, bf16 output
// ===========================================================================
__global__ __launch_bounds__(256) void sae15_gemm(const unsigned short* __restrict__ xb,
                                                  const unsigned short* __restrict__ wb,
                                                  const float* __restrict__ benc,
                                                  unsigned short* __restrict__ Yb)
{
    __shared__ unsigned short Als[4 * APLANE];
    __shared__ unsigned short Bls[4 * APLANE];

    const int tid  = threadIdx.x;
    const int row0 = blockIdx.y * GBM;
    const int col0 = blockIdx.x * GBN;
    const int wid  = tid >> 6;
    const int lane = tid & 63;
    const int wr = wid >> 1;
    const int wc = wid & 1;
    const int fr = lane & 15;
    const int kg = lane >> 4;

    f32x4 acc[4][4];
#pragma unroll
    for (int i = 0; i < 4; ++i)
#pragma unroll
        for (int j = 0; j < 4; ++j) acc[i][j] = (f32x4){0.f, 0.f, 0.f, 0.f};

    for (int kt = 0; kt < DIM; kt += GBK) {
#pragma unroll
        for (int i = 0; i < 4; ++i) {
            const int idx = i * 256 + tid;
            const int r   = idx >> 3;
            const int kq  = (idx & 7) * 4;
            const int g   = kq >> 3;
            const int k0  = kq & 7;
            *(uint2*)&Als[g * APLANE + r * AROW + k0] =
                *(const uint2*)(xb + (size_t)(row0 + r) * DIM + kt + kq);
            *(uint2*)&Bls[g * APLANE + r * AROW + k0] =
                *(const uint2*)(wb + (size_t)(col0 + r) * DIM + kt + kq);
        }
        __syncthreads();

        bf16x8 afr[4], bfr[4];
#pragma unroll
        for (int mi = 0; mi < 4; ++mi)
            afr[mi] = *(const bf16x8*)&Als[kg * APLANE + (wr * 64 + mi * 16 + fr) * AROW];
#pragma unroll
        for (int ni = 0; ni < 4; ++ni)
            bfr[ni] = *(const bf16x8*)&Bls[kg * APLANE + (wc * 64 + ni * 16 + fr) * AROW];
#pragma unroll
        for (int mi = 0; mi < 4; ++mi)
#pragma unroll
            for (int ni = 0; ni < 4; ++ni)
                acc[mi][ni] = __builtin_amdgcn_mfma_f32_16x16x32_bf16(
                    afr[mi], bfr[ni], acc[mi][ni], 0, 0, 0);
        __syncthreads();
    }

#pragma unroll
    for (int ni = 0; ni < 4; ++ni) {
        const int col = col0 + wc * 64 + ni * 16 + fr;
        const float be = benc[col];
#pragma unroll
        for (int mi = 0; mi < 4; ++mi) {
            const int rbase = row0 + wr * 64 + mi * 16 + kg * 4;
#pragma unroll
            for (int j = 0; j < 4; ++j)
                Yb[(size_t)(rbase + j) * FEAT + col] =
                    bf16r(fmaxf(acc[mi][ni][j] + be, 0.f));
        }
    }
}

// ===========================================================================
// W_dec transpose
// ===========================================================================
__global__ void sae15_wt(const float* __restrict__ Wdec, float* __restrict__ Wt)
{
    __shared__ float t[32][33];
    const int f0 = blockIdx.x * 32;
    const int d0 = blockIdx.y * 32;
    const int tx = threadIdx.x;
    const int ty = threadIdx.y;
#pragma unroll
    for (int i = 0; i < 4; ++i)
        t[ty + i * 8][tx] = Wdec[(size_t)(d0 + ty + i * 8) * FEAT + f0 + tx];
    __syncthreads();
#pragma unroll
    for (int i = 0; i < 4; ++i)
        Wt[(size_t)(f0 + ty + i * 8) * DIM + d0 + tx] = t[tx][ty + i * 8];
}

// ===========================================================================
// 14-bit histogram over bf16 Y bits
// ===========================================================================
__global__ __launch_bounds__(1024) void sae15_hist(const unsigned short* __restrict__ Yb,
                                                   unsigned* __restrict__ hist)
{
    __shared__ unsigned h[16384];
    const int t = threadIdx.x;
    for (int i = t; i < 16384; i += 1024) h[i] = 0u;
    __syncthreads();
    const uint4* Y8 = (const uint4*)Yb;
    const int total8 = N_TOT / 8;
    for (int i = blockIdx.x * 1024 + t; i < total8; i += gridDim.x * 1024) {
        uint4 v = Y8[i];
        unsigned w[4] = {v.x, v.y, v.z, v.w};
#pragma unroll
        for (int k = 0; k < 4; ++k) {
            unsigned lo = w[k] & 0xFFFFu;
            unsigned hi = w[k] >> 16;
            if (lo) atomicAdd(&h[lo >> 2], 1u);
            if (hi) atomicAdd(&h[hi >> 2], 1u);
        }
    }
    __syncthreads();
    for (int i = t; i < 16384; i += 1024) {
        unsigned c = h[i];
        if (c) atomicAdd(&hist[i], c);
    }
}

// ===========================================================================
// Prune-threshold select
// ===========================================================================
__global__ __launch_bounds__(1024) void sae15_selb(const unsigned* __restrict__ hist,
                                                   unsigned* sl)
{
    __shared__ unsigned s[1024];
    const int t = threadIdx.x;
    const int C = 16;
    const unsigned N = (unsigned)(KB_SEL + MARGIN);
    const int lo = t * C;
    unsigned S = 0;
    for (int i = 0; i < C; ++i) S += hist[lo + i];
    s[t] = S;
    __syncthreads();
    for (int off = 1; off < 1024; off <<= 1) {
        unsigned v = (t + off < 1024) ? s[t + off] : 0u;
        __syncthreads();
        s[t] += v;
        __syncthreads();
    }
    const unsigned incl  = s[t];
    const unsigned above = incl - S;
    if (above < N && N <= incl) {
        unsigned cum = above;
        for (int i = lo + C - 1; i >= lo; --i) {
            cum += hist[i];
            if (cum >= N) { sl[SL_T32] = (unsigned)i << 2; break; }
        }
    }
}

// ===========================================================================
// Candidate compact — BLOCK-STAGED
// ===========================================================================
__global__ __launch_bounds__(256) void sae15_cand(const unsigned short* __restrict__ Yb,
                                                  unsigned* __restrict__ sl,
                                                  int* __restrict__ cand_raw)
{
    __shared__ int      loc[LSTAGE];
    __shared__ unsigned lcnt;
    __shared__ unsigned gbase;
    if (threadIdx.x == 0) lcnt = 0;
    __syncthreads();

    const unsigned T = sl[SL_T32];
    const uint4* Y8 = (const uint4*)Yb;
    const int total8 = N_TOT / 8;
    for (int i = blockIdx.x * blockDim.x + threadIdx.x; i < total8;
         i += gridDim.x * blockDim.x) {
        uint4 v = Y8[i];
        unsigned w[4] = {v.x, v.y, v.z, v.w};
#pragma unroll
        for (int k = 0; k < 4; ++k) {
            unsigned lo = w[k] & 0xFFFFu;
            unsigned hi = w[k] >> 16;
            if (lo >= T) {
                unsigned p = atomicAdd(&lcnt, 1u);
                if (p < (unsigned)LSTAGE) loc[p] = i * 8 + k * 2;
            }
            if (hi >= T) {
                unsigned p = atomicAdd(&lcnt, 1u);
                if (p < (unsigned)LSTAGE) loc[p] = i * 8 + k * 2 + 1;
            }
        }
    }
    __syncthreads();
    unsigned n = lcnt;
    if (n > (unsigned)LSTAGE) n = (unsigned)LSTAGE;
    if (threadIdx.x == 0) gbase = atomicAdd(&sl[SL_NC], n);
    __syncthreads();
    const unsigned base = gbase;
    for (unsigned k = threadIdx.x; k < n; k += blockDim.x) {
        unsigned dst = base + k;
        if (dst < (unsigned)CCAP) cand_raw[dst] = loc[k];
    }
}

// ===========================================================================
// Feature-major candidate reorder (round-19): counting sort by feature id.
// Round-18 profile: feval at 121us / 305MB FETCH — batch-major candidate
// order makes consecutive waves read DIFFERENT Wenc rows (50MB array, 4MB
// L2/XCD -> ~every row load misses L2). Feature-major order puts the ~10
// candidates sharing a feature adjacent -> Wenc row loaded once, reused.
// Selection is order-invariant (exact f64 keys + index ties).
// ===========================================================================
__global__ __launch_bounds__(256) void sae15_fhist(const int* __restrict__ cand_raw,
                                                   const unsigned* __restrict__ sl,
                                                   unsigned* __restrict__ fhist)
{
    __shared__ unsigned h[16384];
    const int t = threadIdx.x;
    for (int i = t; i < 16384; i += 256) h[i] = 0u;
    __syncthreads();
    unsigned NC = sl[SL_NC];
    if (NC > (unsigned)CCAP) NC = (unsigned)CCAP;
    for (int i = blockIdx.x * 256 + t; i < (int)NC; i += gridDim.x * 256)
        atomicAdd(&h[cand_raw[i] & (FEAT - 1)], 1u);
    __syncthreads();
    for (int i = t; i < 16384; i += 256) {
        unsigned c = h[i];
        if (c) atomicAdd(&fhist[i], c);
    }
}

__global__ __launch_bounds__(1024) void sae15_fscan(const unsigned* __restrict__ fhist,
                                                    unsigned* __restrict__ fofs)
{
    __shared__ unsigned s[1024];
    const int t = threadIdx.x;
    unsigned c[16];
    unsigned sum = 0;
#pragma unroll
    for (int j = 0; j < 16; ++j) { c[j] = fhist[t * 16 + j]; sum += c[j]; }
    s[t] = sum;
    __syncthreads();
    for (int off = 1; off < 1024; off <<= 1) {
        unsigned v = (t >= off) ? s[t - off] : 0u;
        __syncthreads();
        s[t] += v;
        __syncthreads();
    }
    unsigned run = s[t] - sum;
#pragma unroll
    for (int j = 0; j < 16; ++j) { fofs[t * 16 + j] = run; run += c[j]; }
}

__global__ __launch_bounds__(256) void sae15_fscat(const int* __restrict__ cand_raw,
                                                   const unsigned* __restrict__ sl,
                                                   const unsigned* __restrict__ fofs,
                                                   unsigned* __restrict__ fcur,
                                                   int* __restrict__ cand_flat)
{
    unsigned NC = sl[SL_NC];
    if (NC > (unsigned)CCAP) NC = (unsigned)CCAP;
    for (int i = blockIdx.x * 256 + threadIdx.x; i < (int)NC; i += gridDim.x * 256) {
        int flat = cand_raw[i];
        int f = flat & (FEAT - 1);
        unsigned p = atomicAdd(&fcur[f], 1u);
        unsigned dst = fofs[f] + p;
        if (dst < (unsigned)CCAP) cand_flat[dst] = flat;
    }
}

// ===========================================================================
// f64 exact evaluation — one wave per candidate, feature-major order
// ===========================================================================
__global__ __launch_bounds__(256) void sae15_feval(const float* __restrict__ x,
                                                   const float* __restrict__ Wenc,
                                                   const float* __restrict__ benc,
                                                   const float* __restrict__ bdec,
                                                   const unsigned* __restrict__ sl,
                                                   const int* __restrict__ cand_flat,
                                                   u64* __restrict__ cand_key)
{
    unsigned NC = sl[SL_NC];
    if (NC > (unsigned)CCAP) NC = (unsigned)CCAP;
    const int wid  = (blockIdx.x * 256 + threadIdx.x) >> 6;
    const int lane = threadIdx.x & 63;
    if (wid >= (int)NC) return;
    const int flat = cand_flat[wid];
    const int b = flat >> 14;
    const int f = flat & (FEAT - 1);
    const float* xr = x + (size_t)b * DIM;
    const float* wr = Wenc + (size_t)f * DIM;
    double p = 0.0;
#pragma unroll
    for (int d = lane; d < DIM; d += 64)
        p = fma((double)xr[d] - (double)bdec[d], (double)wr[d], p);
#pragma unroll
    for (int o = 32; o > 0; o >>= 1) p += __shfl_xor(p, o, 64);
    if (lane == 0) {
        p += (double)benc[f];
        if (p < 0.0) p = 0.0;
        cand_key[wid] = (u64)__double_as_longlong(p);
    }
}

// ===========================================================================
// u64 radix histogram — 3 LDS-privatized 14-bit passes (42-bit prefix)
// ===========================================================================
__global__ __launch_bounds__(256) void sae15_hist64(const u64* __restrict__ cand_key,
                                                    const unsigned* __restrict__ sl,
                                                    unsigned* __restrict__ hist,
                                                    int pass)
{
    __shared__ unsigned h[16384];
    const int t = threadIdx.x;
    for (int i = t; i < 16384; i += 256) h[i] = 0u;
    __syncthreads();

    unsigned NC = sl[SL_NC];
    if (NC > (unsigned)CCAP) NC = (unsigned)CCAP;
    u64 pref = 0;
    for (int i = 0; i < pass; ++i) pref = (pref << 14) | (u64)sl[SL_S0 + i];
    const int chk_sh = 64 - 14 * pass;
    const int bkt_sh = 50 - 14 * pass;

    for (int i = blockIdx.x * 256 + t; i < (int)NC; i += gridDim.x * 256) {
        u64 key = cand_key[i];
        if (pass > 0 && (key >> chk_sh) != pref) continue;
        atomicAdd(&h[(unsigned)(key >> bkt_sh) & 0x3FFFu], 1u);
    }
    __syncthreads();
    for (int i = t; i < 16384; i += 256) {
        unsigned c = h[i];
        if (c) atomicAdd(&hist[i], c);
    }
}

// ===========================================================================
// 14-bit k-th select per radix pass (rank-K)
// ===========================================================================
__global__ __launch_bounds__(1024) void sae15_sel14(const unsigned* __restrict__ hist,
                                                    unsigned* sl, int pass)
{
    __shared__ unsigned s[1024];
    const int t = threadIdx.x;
    const int C = 16;
    const unsigned N = (pass == 0) ? (unsigned)KB_SEL : sl[SL_S0 + 4 + pass - 1];
    const int lo = t * C;
    unsigned S = 0;
    for (int i = 0; i < C; ++i) S += hist[lo + i];
    s[t] = S;
    __syncthreads();
    for (int off = 1; off < 1024; off <<= 1) {
        unsigned v = (t + off < 1024) ? s[t + off] : 0u;
        __syncthreads();
        s[t] += v;
        __syncthreads();
    }
    const unsigned incl  = s[t];
    const unsigned above = incl - S;
    if (above < N && N <= incl) {
        unsigned cum = above;
        for (int i = lo + C - 1; i >= lo; --i) {
            cum += hist[i];
            if (cum >= N) {
                sl[SL_S0 + pass]     = (unsigned)i;
                sl[SL_S0 + 4 + pass] = N - (cum - hist[i]);
                break;
            }
        }
    }
}

// ===========================================================================
// Max key strictly below rank-K prefix group == rank-(K+1) key
// ===========================================================================
__global__ __launch_bounds__(256) void sae15_maxb(const u64* __restrict__ cand_key,
                                                  const unsigned* __restrict__ sl,
                                                  u64* __restrict__ mx)
{
    unsigned NC = sl[SL_NC];
    if (NC > (unsigned)CCAP) NC = (unsigned)CCAP;
    const u64 Tsh1 = ((u64)sl[SL_S0 + 0] << 28) | ((u64)sl[SL_S0 + 1] << 14) |
                     (u64)sl[SL_S0 + 2];
    u64 m = 0;
    for (int i = blockIdx.x * 256 + threadIdx.x; i < (int)NC; i += gridDim.x * 256) {
        u64 k = cand_key[i];
        if ((k >> 22) < Tsh1 && k > m) m = k;
    }
#pragma unroll
    for (int o = 32; o > 0; o >>= 1) {
        u64 o2 = __shfl_xor(m, o, 64);
        if (o2 > m) m = o2;
    }
    if ((threadIdx.x & 63) == 0 && m) atomicMax((unsigned long long*)mx, m);
}

// ===========================================================================
// Final classify with BOUNDARY SWAP (42-bit prefixes)
// ===========================================================================
__global__ __launch_bounds__(256) void sae15_class(const u64* __restrict__ cand_key,
                                                   const int* __restrict__ cand_flat,
                                                   const u64* __restrict__ mx,
                                                   unsigned* __restrict__ sl,
                                                   unsigned* __restrict__ row_cnt,
                                                   int* __restrict__ sel_flat,
                                                   float* __restrict__ sel_val,
                                                   int* __restrict__ tie_flat,
                                                   u64* __restrict__ tie_key)
{
    unsigned NC = sl[SL_NC];
    if (NC > (unsigned)CCAP) NC = (unsigned)CCAP;
    const u64 Tsh1 = ((u64)sl[SL_S0 + 0] << 28) | ((u64)sl[SL_S0 + 1] << 14) |
                     (u64)sl[SL_S0 + 2];
    const u64 Tsh2 = mx[0] >> 22;
    const int c = blockIdx.x * 256 + threadIdx.x;
    const bool active = (c < (int)NC);
    u64 key = 0;
    int flat = 0;
    u64 keysh = 0;
    if (active) {
        key = cand_key[c];
        keysh = key >> 22;
        flat = cand_flat[c];
    }
    const bool selp = active && (keysh > Tsh1);
    unsigned p = wave_append(&sl[SL_DEF], selp);
    if (selp && p < (unsigned)KB_SEL) {
        sel_flat[p] = flat;
        sel_val[p]  = (float)__longlong_as_double((long long)key);
        atomicAdd(&row_cnt[flat >> 14], 1u);
    }
    const bool tiep = active && !selp && (keysh == Tsh2);
    unsigned q = wave_append(&sl[SL_NTIE], tiep);
    if (tiep && q < (unsigned)TIE_CAP) { tie_flat[q] = flat; tie_key[q] = key; }
}

// ===========================================================================
// Tie/swap resolve: REM lowest flat indices
// ===========================================================================
__global__ __launch_bounds__(256) void sae15_ties(const int* __restrict__ tie_flat,
                                                  const u64* __restrict__ tie_key,
                                                  unsigned* __restrict__ sl,
                                                  int* __restrict__ sel_flat,
                                                  float* __restrict__ sel_val,
                                                  unsigned* __restrict__ row_cnt)
{
    unsigned R = sl[SL_NTIE];
    if (R > (unsigned)TIE_CAP) R = (unsigned)TIE_CAP;
    const unsigned REM = sl[SL_S0 + 6];
    const unsigned D = sl[SL_DEF];
    const int c = blockIdx.x * blockDim.x + threadIdx.x;
    if (c >= (int)R) return;
    const int ic = tie_flat[c];
    unsigned rank = 0;
    for (int j = 0; j < (int)R; ++j)
        if (tie_flat[j] < ic) ++rank;
    if (rank < REM) {
        unsigned p = D + atomicAdd(&sl[SL_WIN], 1u);
        if (p < (unsigned)KB_SEL) {
            sel_flat[p] = ic;
            sel_val[p]  = (float)__longlong_as_double((long long)tie_key[c]);
            atomicAdd(&row_cnt[ic >> 14], 1u);
        }
    }
}

// ===========================================================================
// Row prefix sum
// ===========================================================================
__global__ __launch_bounds__(256) void sae15_scan(const unsigned* __restrict__ row_cnt,
                                                  unsigned* __restrict__ row_ofs)
{
    __shared__ unsigned s[256];
    const int t = threadIdx.x;
    unsigned c[8];
    unsigned sum = 0;
#pragma unroll
    for (int j = 0; j < 8; ++j) { c[j] = row_cnt[t * 8 + j]; sum += c[j]; }
    s[t] = sum;
    __syncthreads();
    for (int off = 1; off < 256; off <<= 1) {
        unsigned v = (t >= off) ? s[t - off] : 0u;
        __syncthreads();
        s[t] += v;
        __syncthreads();
    }
    unsigned run = s[t] - sum;
#pragma unroll
    for (int j = 0; j < 8; ++j) { row_ofs[t * 8 + j] = run; run += c[j]; }
    if (t == 255) row_ofs[2048] = run;
}

// ===========================================================================
// Scatter into row-grouped arrays
// ===========================================================================
__global__ void sae15_scatter(const int* __restrict__ sel_flat,
                              const float* __restrict__ sel_val,
                              const unsigned* __restrict__ row_ofs,
                              unsigned* __restrict__ cursor,
                              int* __restrict__ gf, float* __restrict__ gv)
{
    int e = blockIdx.x * blockDim.x + threadIdx.x;
    if (e >= KB_SEL) return;
    int flat = sel_flat[e];
    int b = flat >> 14;
    unsigned p = atomicAdd(&cursor[b], 1u);
    unsigned dst = row_ofs[b] + p;
    if (dst < (unsigned)KB_SEL) {
        gf[dst] = flat & (FEAT - 1);
        gv[dst] = sel_val[e];
    }
}

// ===========================================================================
// Sparse decode
// ===========================================================================
__global__ __launch_bounds__(256) void sae15_decode(const int* __restrict__ gf,
                                                    const float* __restrict__ gv,
                                                    const unsigned* __restrict__ row_ofs,
                                                    const float* __restrict__ Wt,
                                                    const float* __restrict__ bdec,
                                                    float* __restrict__ out)
{
    const int b = blockIdx.x;
    const int t = threadIdx.x;
    float a0 = 0.f, a1 = 0.f, a2 = 0.f;
    const unsigned s = row_ofs[b];
    const unsigned e = row_ofs[b + 1];
    for (unsigned i = s; i < e; ++i) {
        const int f   = gf[i];
        const float v = gv[i];
        const float* w = Wt + (size_t)f * DIM;
        a0 = fmaf(v, w[t], a0);
        a1 = fmaf(v, w[t + 256], a1);
        a2 = fmaf(v, w[t + 512], a2);
    }
    out[(size_t)b * DIM + t]       = a0 + bdec[t];
    out[(size_t)b * DIM + t + 256] = a1 + bdec[t + 256];
    out[(size_t)b * DIM + t + 512] = a2 + bdec[t + 512];
}

// ===========================================================================
extern "C" void kernel_launch(void* const* d_in, const int* in_sizes, int n_in,
                              void* d_out, int out_size, void* d_ws, size_t ws_size,
                              hipStream_t stream)
{
    (void)in_sizes; (void)n_in; (void)out_size;
    const float* x    = (const float*)d_in[0];
    const float* Wenc = (const float*)d_in[1];
    const float* benc = (const float*)d_in[2];
    const float* Wdec = (const float*)d_in[3];
    const float* bdec = (const float*)d_in[4];
    float* out = (float*)d_out;

    char* ws = (char*)d_ws;
    size_t off = 0;
    unsigned short* Yb  = (unsigned short*)(ws + off);     off += (size_t)N_TOT * 2;
    float*    Wt        = (float*)(ws + off);              off += (size_t)FEAT * DIM * 4;
    unsigned short* xb  = (unsigned short*)(ws + off);     off += (size_t)BATCH * DIM * 2;
    unsigned short* wb  = (unsigned short*)(ws + off);     off += (size_t)FEAT * DIM * 2;
    u64*      cand_key  = (u64*)(ws + off);                off += (size_t)CCAP * 8;
    int*      cand_raw  = (int*)(ws + off);                off += (size_t)CCAP * 4;
    int*      cand_flat = (int*)(ws + off);                off += (size_t)CCAP * 4;
    int*      tie_flat  = (int*)(ws + off);                off += (size_t)TIE_CAP * 4;
    u64*      tie_key   = (u64*)(ws + off);                off += (size_t)TIE_CAP * 8;
    unsigned* row_ofs   = (unsigned*)(ws + off);           off += 2052 * 4;
    unsigned* fofs      = (unsigned*)(ws + off);           off += 16384 * 4;
    // ---- contiguous ZERO ZONE (single memset) ----
    char* zstart = ws + off;
    int*      sel_flat  = (int*)(ws + off);                off += (size_t)KB_SEL * 4;
    float*    sel_val   = (float*)(ws + off);              off += (size_t)KB_SEL * 4;
    int*      gf        = (int*)(ws + off);                off += (size_t)KB_SEL * 4;
    float*    gv        = (float*)(ws + off);              off += (size_t)KB_SEL * 4;
    unsigned* hist1     = (unsigned*)(ws + off);           off += 16384 * 4;
    unsigned* h64       = (unsigned*)(ws + off);           off += 3 * 16384 * 4;
    unsigned* fhist     = (unsigned*)(ws + off);           off += 16384 * 4;
    unsigned* fcur      = (unsigned*)(ws + off);           off += 16384 * 4;
    unsigned* row_cnt   = (unsigned*)(ws + off);           off += 2048 * 4;
    unsigned* cursor    = (unsigned*)(ws + off);           off += 2048 * 4;
    u64*      mx        = (u64*)(ws + off);                off += 8;
    unsigned* sl        = (unsigned*)(ws + off);           off += 256;
    const size_t zbytes = (size_t)((ws + off) - zstart);
    if (ws_size < off) return;

    hipMemsetAsync(zstart, 0, zbytes, stream);

    // pre-convert + decoder transpose + encode GEMM
    sae15_prep<<<4096, 256, 0, stream>>>(x, Wenc, bdec, xb, wb);
    sae15_wt<<<dim3(FEAT / 32, DIM / 32), dim3(32, 8), 0, stream>>>(Wdec, Wt);
    sae15_gemm<<<dim3(FEAT / GBN, BATCH / GBM), 256, 0, stream>>>(xb, wb, benc, Yb);

    // prune threshold (one pass over bf16 Y)
    sae15_hist<<<512, 1024, 0, stream>>>(Yb, hist1);
    sae15_selb<<<1, 1024, 0, stream>>>(hist1, sl);

    // candidates -> feature-major reorder -> exact f64 keys
    sae15_cand<<<2048, 256, 0, stream>>>(Yb, sl, cand_raw);
    sae15_fhist<<<256, 256, 0, stream>>>(cand_raw, sl, fhist);
    sae15_fscan<<<1, 1024, 0, stream>>>(fhist, fofs);
    sae15_fscat<<<256, 256, 0, stream>>>(cand_raw, sl, fofs, fcur, cand_flat);
    sae15_feval<<<(CCAP + 3) / 4, 256, 0, stream>>>(x, Wenc, benc, bdec, sl, cand_flat, cand_key);

    // rank-K 42-bit prefix (3 passes) + rank-(K+1) via max-below
    for (int p = 0; p < 3; ++p) {
        sae15_hist64<<<256, 256, 0, stream>>>(cand_key, sl, h64 + p * 16384, p);
        sae15_sel14<<<1, 1024, 0, stream>>>(h64 + p * 16384, sl, p);
    }
    sae15_maxb<<<256, 256, 0, stream>>>(cand_key, sl, mx);

    // selection with rank-K <-> rank-(K+1) boundary swap
    sae15_class<<<(CCAP + 255) / 256, 256, 0, stream>>>(cand_key, cand_flat, mx, sl, row_cnt,
                                                        sel_flat, sel_val, tie_flat, tie_key);
    sae15_ties<<<TIE_CAP / 256, 256, 0, stream>>>(tie_flat, tie_key, sl,
                                                  sel_flat, sel_val, row_cnt);

    // group by batch row and decode sparsely
    sae15_scan<<<1, 256, 0, stream>>>(row_cnt, row_ofs);
    sae15_scatter<<<(KB_SEL + 255) / 256, 256, 0, stream>>>(sel_flat, sel_val, row_ofs, cursor, gf, gv);
    sae15_decode<<<BATCH, 256, 0, stream>>>(gf, gv, row_ofs, Wt, bdec, out);
}

// Round 20
// 462.797 us; speedup vs baseline: 1.0885x; 1.0885x over previous
//
#include <hip/hip_runtime.h>
#include <stdint.h>

// Problem constants
#define BATCH   2048
#define DIM     768
#define FEAT    16384
#define KSEL    64
#define KB_SEL  (BATCH * KSEL)      // 131072 selected
#define N_TOT   (BATCH * FEAT)      // 33554432
#define NX4     (BATCH * DIM / 4)
#define NW4     (FEAT * DIM / 4)

// MFMA GEMM tiling
#define GBM 128
#define GBN 128
#define GBK 32
#define AROW   24
#define APLANE 3088

// Margin: Y(bf16 out of bf16 MFMA) vs f64 max err ~7e-3; 32768 ranks ~34e-3 band
#define MARGIN  32768
#define CCAP    229376
#define TIE_CAP 1024
#define LSTAGE  2048
#define FG      8                   // candidates per wave in feval
#define FBLK    (CCAP / (FG * 4))   // 7168 blocks (7168 % 8 == 0 -> bijective swizzle)

// scalar slots
#define SL_T32    0
#define SL_NC     1
#define SL_DEF    2
#define SL_NTIE   3
#define SL_WIN    4
#define SL_S0     16

typedef __attribute__((ext_vector_type(8))) __bf16 bf16x8;
typedef __attribute__((ext_vector_type(4))) float  f32x4;
typedef unsigned long long u64;

__device__ __forceinline__ unsigned short bf16r(float v)
{
    unsigned u = __float_as_uint(v);
    u += 0x7FFFu + ((u >> 16) & 1u);
    return (unsigned short)(u >> 16);
}

__device__ __forceinline__ unsigned wave_append(unsigned* counter, bool pred)
{
    unsigned long long m = __ballot(pred);
    if (m == 0ull) return 0xFFFFFFFFu;
    const int lane = threadIdx.x & 63;
    const int leader = __ffsll((unsigned long long)m) - 1;
    unsigned base = 0;
    if (lane == leader) base = atomicAdd(counter, (unsigned)__popcll(m));
    base = __shfl(base, leader, 64);
    if (!pred) return 0xFFFFFFFFu;
    return base + (unsigned)__popcll(m & ((1ull << lane) - 1ull));
}

// ===========================================================================
// Pre-convert: xb = bf16(x - bdec), wb = bf16(Wenc), once
// ===========================================================================
__global__ __launch_bounds__(256) void sae16_prep(const float* __restrict__ x,
                                                  const float* __restrict__ Wenc,
                                                  const float* __restrict__ bdec,
                                                  unsigned short* __restrict__ xb,
                                                  unsigned short* __restrict__ wb)
{
    const int tot = NX4 + NW4;
    for (int i = blockIdx.x * 256 + threadIdx.x; i < tot; i += gridDim.x * 256) {
        if (i < NX4) {
            const int e = i * 4;
            const int d = e % DIM;
            float4 v  = *(const float4*)(x + e);
            float4 dv = *(const float4*)(bdec + d);
            uint2 p;
            p.x = (unsigned)bf16r(v.x - dv.x) | ((unsigned)bf16r(v.y - dv.y) << 16);
            p.y = (unsigned)bf16r(v.z - dv.z) | ((unsigned)bf16r(v.w - dv.w) << 16);
            *(uint2*)(xb + e) = p;
        } else {
            const int e = (i - NX4) * 4;
            float4 v = *(const float4*)(Wenc + e);
            uint2 p;
            p.x = (unsigned)bf16r(v.x) | ((unsigned)bf16r(v.y) << 16);
            p.y = (unsigned)bf16r(v.z) | ((unsigned)bf16r(v.w) << 16);
            *(uint2*)(wb + e) = p;
        }
    }
}

// ===========================================================================
// Encode GEMM — bf16 MFMA from pre-converted inputs, bf16 output
// ===========================================================================
__global__ __launch_bounds__(256) void sae16_gemm(const unsigned short* __restrict__ xb,
                                                  const unsigned short* __restrict__ wb,
                                                  const float* __restrict__ benc,
                                                  unsigned short* __restrict__ Yb)
{
    __shared__ unsigned short Als[4 * APLANE];
    __shared__ unsigned short Bls[4 * APLANE];

    const int tid  = threadIdx.x;
    const int row0 = blockIdx.y * GBM;
    const int col0 = blockIdx.x * GBN;
    const int wid  = tid >> 6;
    const int lane = tid & 63;
    const int wr = wid >> 1;
    const int wc = wid & 1;
    const int fr = lane & 15;
    const int kg = lane >> 4;

    f32x4 acc[4][4];
#pragma unroll
    for (int i = 0; i < 4; ++i)
#pragma unroll
        for (int j = 0; j < 4; ++j) acc[i][j] = (f32x4){0.f, 0.f, 0.f, 0.f};

    for (int kt = 0; kt < DIM; kt += GBK) {
#pragma unroll
        for (int i = 0; i < 4; ++i) {
            const int idx = i * 256 + tid;
            const int r   = idx >> 3;
            const int kq  = (idx & 7) * 4;
            const int g   = kq >> 3;
            const int k0  = kq & 7;
            *(uint2*)&Als[g * APLANE + r * AROW + k0] =
                *(const uint2*)(xb + (size_t)(row0 + r) * DIM + kt + kq);
            *(uint2*)&Bls[g * APLANE + r * AROW + k0] =
                *(const uint2*)(wb + (size_t)(col0 + r) * DIM + kt + kq);
        }
        __syncthreads();

        bf16x8 afr[4], bfr[4];
#pragma unroll
        for (int mi = 0; mi < 4; ++mi)
            afr[mi] = *(const bf16x8*)&Als[kg * APLANE + (wr * 64 + mi * 16 + fr) * AROW];
#pragma unroll
        for (int ni = 0; ni < 4; ++ni)
            bfr[ni] = *(const bf16x8*)&Bls[kg * APLANE + (wc * 64 + ni * 16 + fr) * AROW];
#pragma unroll
        for (int mi = 0; mi < 4; ++mi)
#pragma unroll
            for (int ni = 0; ni < 4; ++ni)
                acc[mi][ni] = __builtin_amdgcn_mfma_f32_16x16x32_bf16(
                    afr[mi], bfr[ni], acc[mi][ni], 0, 0, 0);
        __syncthreads();
    }

#pragma unroll
    for (int ni = 0; ni < 4; ++ni) {
        const int col = col0 + wc * 64 + ni * 16 + fr;
        const float be = benc[col];
#pragma unroll
        for (int mi = 0; mi < 4; ++mi) {
            const int rbase = row0 + wr * 64 + mi * 16 + kg * 4;
#pragma unroll
            for (int j = 0; j < 4; ++j)
                Yb[(size_t)(rbase + j) * FEAT + col] =
                    bf16r(fmaxf(acc[mi][ni][j] + be, 0.f));
        }
    }
}

// ===========================================================================
// W_dec transpose
// ===========================================================================
__global__ void sae16_wt(const float* __restrict__ Wdec, float* __restrict__ Wt)
{
    __shared__ float t[32][33];
    const int f0 = blockIdx.x * 32;
    const int d0 = blockIdx.y * 32;
    const int tx = threadIdx.x;
    const int ty = threadIdx.y;
#pragma unroll
    for (int i = 0; i < 4; ++i)
        t[ty + i * 8][tx] = Wdec[(size_t)(d0 + ty + i * 8) * FEAT + f0 + tx];
    __syncthreads();
#pragma unroll
    for (int i = 0; i < 4; ++i)
        Wt[(size_t)(f0 + ty + i * 8) * DIM + d0 + tx] = t[tx][ty + i * 8];
}

// ===========================================================================
// 14-bit histogram over bf16 Y bits
// ===========================================================================
__global__ __launch_bounds__(1024) void sae16_hist(const unsigned short* __restrict__ Yb,
                                                   unsigned* __restrict__ hist)
{
    __shared__ unsigned h[16384];
    const int t = threadIdx.x;
    for (int i = t; i < 16384; i += 1024) h[i] = 0u;
    __syncthreads();
    const uint4* Y8 = (const uint4*)Yb;
    const int total8 = N_TOT / 8;
    for (int i = blockIdx.x * 1024 + t; i < total8; i += gridDim.x * 1024) {
        uint4 v = Y8[i];
        unsigned w[4] = {v.x, v.y, v.z, v.w};
#pragma unroll
        for (int k = 0; k < 4; ++k) {
            unsigned lo = w[k] & 0xFFFFu;
            unsigned hi = w[k] >> 16;
            if (lo) atomicAdd(&h[lo >> 2], 1u);
            if (hi) atomicAdd(&h[hi >> 2], 1u);
        }
    }
    __syncthreads();
    for (int i = t; i < 16384; i += 1024) {
        unsigned c = h[i];
        if (c) atomicAdd(&hist[i], c);
    }
}

// ===========================================================================
// Prune-threshold select
// ===========================================================================
__global__ __launch_bounds__(1024) void sae16_selb(const unsigned* __restrict__ hist,
                                                   unsigned* sl)
{
    __shared__ unsigned s[1024];
    const int t = threadIdx.x;
    const int C = 16;
    const unsigned N = (unsigned)(KB_SEL + MARGIN);
    const int lo = t * C;
    unsigned S = 0;
    for (int i = 0; i < C; ++i) S += hist[lo + i];
    s[t] = S;
    __syncthreads();
    for (int off = 1; off < 1024; off <<= 1) {
        unsigned v = (t + off < 1024) ? s[t + off] : 0u;
        __syncthreads();
        s[t] += v;
        __syncthreads();
    }
    const unsigned incl  = s[t];
    const unsigned above = incl - S;
    if (above < N && N <= incl) {
        unsigned cum = above;
        for (int i = lo + C - 1; i >= lo; --i) {
            cum += hist[i];
            if (cum >= N) { sl[SL_T32] = (unsigned)i << 2; break; }
        }
    }
}

// ===========================================================================
// Candidate compact — BLOCK-STAGED
// ===========================================================================
__global__ __launch_bounds__(256) void sae16_cand(const unsigned short* __restrict__ Yb,
                                                  unsigned* __restrict__ sl,
                                                  int* __restrict__ cand_raw)
{
    __shared__ int      loc[LSTAGE];
    __shared__ unsigned lcnt;
    __shared__ unsigned gbase;
    if (threadIdx.x == 0) lcnt = 0;
    __syncthreads();

    const unsigned T = sl[SL_T32];
    const uint4* Y8 = (const uint4*)Yb;
    const int total8 = N_TOT / 8;
    for (int i = blockIdx.x * blockDim.x + threadIdx.x; i < total8;
         i += gridDim.x * blockDim.x) {
        uint4 v = Y8[i];
        unsigned w[4] = {v.x, v.y, v.z, v.w};
#pragma unroll
        for (int k = 0; k < 4; ++k) {
            unsigned lo = w[k] & 0xFFFFu;
            unsigned hi = w[k] >> 16;
            if (lo >= T) {
                unsigned p = atomicAdd(&lcnt, 1u);
                if (p < (unsigned)LSTAGE) loc[p] = i * 8 + k * 2;
            }
            if (hi >= T) {
                unsigned p = atomicAdd(&lcnt, 1u);
                if (p < (unsigned)LSTAGE) loc[p] = i * 8 + k * 2 + 1;
            }
        }
    }
    __syncthreads();
    unsigned n = lcnt;
    if (n > (unsigned)LSTAGE) n = (unsigned)LSTAGE;
    if (threadIdx.x == 0) gbase = atomicAdd(&sl[SL_NC], n);
    __syncthreads();
    const unsigned base = gbase;
    for (unsigned k = threadIdx.x; k < n; k += blockDim.x) {
        unsigned dst = base + k;
        if (dst < (unsigned)CCAP) cand_raw[dst] = loc[k];
    }
}

// ===========================================================================
// Feature-major candidate reorder (counting sort by feature id)
// ===========================================================================
__global__ __launch_bounds__(256) void sae16_fhist(const int* __restrict__ cand_raw,
                                                   const unsigned* __restrict__ sl,
                                                   unsigned* __restrict__ fhist)
{
    __shared__ unsigned h[16384];
    const int t = threadIdx.x;
    for (int i = t; i < 16384; i += 256) h[i] = 0u;
    __syncthreads();
    unsigned NC = sl[SL_NC];
    if (NC > (unsigned)CCAP) NC = (unsigned)CCAP;
    for (int i = blockIdx.x * 256 + t; i < (int)NC; i += gridDim.x * 256)
        atomicAdd(&h[cand_raw[i] & (FEAT - 1)], 1u);
    __syncthreads();
    for (int i = t; i < 16384; i += 256) {
        unsigned c = h[i];
        if (c) atomicAdd(&fhist[i], c);
    }
}

__global__ __launch_bounds__(1024) void sae16_fscan(const unsigned* __restrict__ fhist,
                                                    unsigned* __restrict__ fofs)
{
    __shared__ unsigned s[1024];
    const int t = threadIdx.x;
    unsigned c[16];
    unsigned sum = 0;
#pragma unroll
    for (int j = 0; j < 16; ++j) { c[j] = fhist[t * 16 + j]; sum += c[j]; }
    s[t] = sum;
    __syncthreads();
    for (int off = 1; off < 1024; off <<= 1) {
        unsigned v = (t >= off) ? s[t - off] : 0u;
        __syncthreads();
        s[t] += v;
        __syncthreads();
    }
    unsigned run = s[t] - sum;
#pragma unroll
    for (int j = 0; j < 16; ++j) { fofs[t * 16 + j] = run; run += c[j]; }
}

__global__ __launch_bounds__(256) void sae16_fscat(const int* __restrict__ cand_raw,
                                                   const unsigned* __restrict__ sl,
                                                   const unsigned* __restrict__ fofs,
                                                   unsigned* __restrict__ fcur,
                                                   int* __restrict__ cand_flat)
{
    unsigned NC = sl[SL_NC];
    if (NC > (unsigned)CCAP) NC = (unsigned)CCAP;
    for (int i = blockIdx.x * 256 + threadIdx.x; i < (int)NC; i += gridDim.x * 256) {
        int flat = cand_raw[i];
        int f = flat & (FEAT - 1);
        unsigned p = atomicAdd(&fcur[f], 1u);
        unsigned dst = fofs[f] + p;
        if (dst < (unsigned)CCAP) cand_flat[dst] = flat;
    }
}

// ===========================================================================
// f64 exact evaluation — FG candidates per wave, register-cached Wenc row,
// XCD-swizzled blocks (round-20).
// Round-19 lesson: feature-sorting alone didn't pay because consecutive
// blocks land on different XCDs (per-XCD L2, block b -> XCD b%8): each
// feature row was re-fetched by ~4 XCDs (FETCH 217MB). Fix: (a) each wave
// owns 8 consecutive sorted candidates and register-caches the w-row across
// same-feature runs; (b) bijective XCD swizzle makes candidate ranges
// contiguous per XCD. Per-candidate f64 math order unchanged -> identical
// keys -> selection unchanged.
// ===========================================================================
__global__ __launch_bounds__(256) void sae16_feval(const float* __restrict__ x,
                                                   const float* __restrict__ Wenc,
                                                   const float* __restrict__ benc,
                                                   const float* __restrict__ bdec,
                                                   const unsigned* __restrict__ sl,
                                                   const int* __restrict__ cand_flat,
                                                   u64* __restrict__ cand_key)
{
    unsigned NC = sl[SL_NC];
    if (NC > (unsigned)CCAP) NC = (unsigned)CCAP;
    const int lane = threadIdx.x & 63;
    // XCD-aware bijective swizzle (FBLK % 8 == 0)
    const int b = blockIdx.x;
    const int lb = (b & 7) * (FBLK / 8) + (b >> 3);
    const int wid = lb * 4 + (threadIdx.x >> 6);
    const int c0 = wid * FG;
    if (c0 >= (int)NC) return;

    float bd[12], wv[12];
#pragma unroll
    for (int j = 0; j < 12; ++j) bd[j] = bdec[lane + j * 64];
    int fprev = -1;

    for (int g = 0; g < FG; ++g) {
        const int c = c0 + g;
        if (c >= (int)NC) break;
        const int flat = cand_flat[c];
        const int bb = flat >> 14;
        const int f  = flat & (FEAT - 1);
        if (f != fprev) {
            const float* wr = Wenc + (size_t)f * DIM;
#pragma unroll
            for (int j = 0; j < 12; ++j) wv[j] = wr[lane + j * 64];
            fprev = f;
        }
        const float* xr = x + (size_t)bb * DIM;
        double p = 0.0;
#pragma unroll
        for (int j = 0; j < 12; ++j)
            p = fma((double)xr[lane + j * 64] - (double)bd[j], (double)wv[j], p);
#pragma unroll
        for (int o = 32; o > 0; o >>= 1) p += __shfl_xor(p, o, 64);
        if (lane == 0) {
            p += (double)benc[f];
            if (p < 0.0) p = 0.0;
            cand_key[c] = (u64)__double_as_longlong(p);
        }
    }
}

// ===========================================================================
// u64 radix histogram — 3 LDS-privatized 14-bit passes (42-bit prefix)
// ===========================================================================
__global__ __launch_bounds__(256) void sae16_hist64(const u64* __restrict__ cand_key,
                                                    const unsigned* __restrict__ sl,
                                                    unsigned* __restrict__ hist,
                                                    int pass)
{
    __shared__ unsigned h[16384];
    const int t = threadIdx.x;
    for (int i = t; i < 16384; i += 256) h[i] = 0u;
    __syncthreads();

    unsigned NC = sl[SL_NC];
    if (NC > (unsigned)CCAP) NC = (unsigned)CCAP;
    u64 pref = 0;
    for (int i = 0; i < pass; ++i) pref = (pref << 14) | (u64)sl[SL_S0 + i];
    const int chk_sh = 64 - 14 * pass;
    const int bkt_sh = 50 - 14 * pass;

    for (int i = blockIdx.x * 256 + t; i < (int)NC; i += gridDim.x * 256) {
        u64 key = cand_key[i];
        if (pass > 0 && (key >> chk_sh) != pref) continue;
        atomicAdd(&h[(unsigned)(key >> bkt_sh) & 0x3FFFu], 1u);
    }
    __syncthreads();
    for (int i = t; i < 16384; i += 256) {
        unsigned c = h[i];
        if (c) atomicAdd(&hist[i], c);
    }
}

// ===========================================================================
// 14-bit k-th select per radix pass (rank-K)
// ===========================================================================
__global__ __launch_bounds__(1024) void sae16_sel14(const unsigned* __restrict__ hist,
                                                    unsigned* sl, int pass)
{
    __shared__ unsigned s[1024];
    const int t = threadIdx.x;
    const int C = 16;
    const unsigned N = (pass == 0) ? (unsigned)KB_SEL : sl[SL_S0 + 4 + pass - 1];
    const int lo = t * C;
    unsigned S = 0;
    for (int i = 0; i < C; ++i) S += hist[lo + i];
    s[t] = S;
    __syncthreads();
    for (int off = 1; off < 1024; off <<= 1) {
        unsigned v = (t + off < 1024) ? s[t + off] : 0u;
        __syncthreads();
        s[t] += v;
        __syncthreads();
    }
    const unsigned incl  = s[t];
    const unsigned above = incl - S;
    if (above < N && N <= incl) {
        unsigned cum = above;
        for (int i = lo + C - 1; i >= lo; --i) {
            cum += hist[i];
            if (cum >= N) {
                sl[SL_S0 + pass]     = (unsigned)i;
                sl[SL_S0 + 4 + pass] = N - (cum - hist[i]);
                break;
            }
        }
    }
}

// ===========================================================================
// Max key strictly below rank-K prefix group == rank-(K+1) key
// ===========================================================================
__global__ __launch_bounds__(256) void sae16_maxb(const u64* __restrict__ cand_key,
                                                  const unsigned* __restrict__ sl,
                                                  u64* __restrict__ mx)
{
    unsigned NC = sl[SL_NC];
    if (NC > (unsigned)CCAP) NC = (unsigned)CCAP;
    const u64 Tsh1 = ((u64)sl[SL_S0 + 0] << 28) | ((u64)sl[SL_S0 + 1] << 14) |
                     (u64)sl[SL_S0 + 2];
    u64 m = 0;
    for (int i = blockIdx.x * 256 + threadIdx.x; i < (int)NC; i += gridDim.x * 256) {
        u64 k = cand_key[i];
        if ((k >> 22) < Tsh1 && k > m) m = k;
    }
#pragma unroll
    for (int o = 32; o > 0; o >>= 1) {
        u64 o2 = __shfl_xor(m, o, 64);
        if (o2 > m) m = o2;
    }
    if ((threadIdx.x & 63) == 0 && m) atomicMax((unsigned long long*)mx, m);
}

// ===========================================================================
// Final classify with BOUNDARY SWAP (42-bit prefixes)
// ===========================================================================
__global__ __launch_bounds__(256) void sae16_class(const u64* __restrict__ cand_key,
                                                   const int* __restrict__ cand_flat,
                                                   const u64* __restrict__ mx,
                                                   unsigned* __restrict__ sl,
                                                   unsigned* __restrict__ row_cnt,
                                                   int* __restrict__ sel_flat,
                                                   float* __restrict__ sel_val,
                                                   int* __restrict__ tie_flat,
                                                   u64* __restrict__ tie_key)
{
    unsigned NC = sl[SL_NC];
    if (NC > (unsigned)CCAP) NC = (unsigned)CCAP;
    const u64 Tsh1 = ((u64)sl[SL_S0 + 0] << 28) | ((u64)sl[SL_S0 + 1] << 14) |
                     (u64)sl[SL_S0 + 2];
    const u64 Tsh2 = mx[0] >> 22;
    const int c = blockIdx.x * 256 + threadIdx.x;
    const bool active = (c < (int)NC);
    u64 key = 0;
    int flat = 0;
    u64 keysh = 0;
    if (active) {
        key = cand_key[c];
        keysh = key >> 22;
        flat = cand_flat[c];
    }
    const bool selp = active && (keysh > Tsh1);
    unsigned p = wave_append(&sl[SL_DEF], selp);
    if (selp && p < (unsigned)KB_SEL) {
        sel_flat[p] = flat;
        sel_val[p]  = (float)__longlong_as_double((long long)key);
        atomicAdd(&row_cnt[flat >> 14], 1u);
    }
    const bool tiep = active && !selp && (keysh == Tsh2);
    unsigned q = wave_append(&sl[SL_NTIE], tiep);
    if (tiep && q < (unsigned)TIE_CAP) { tie_flat[q] = flat; tie_key[q] = key; }
}

// ===========================================================================
// Tie/swap resolve: REM lowest flat indices
// ===========================================================================
__global__ __launch_bounds__(256) void sae16_ties(const int* __restrict__ tie_flat,
                                                  const u64* __restrict__ tie_key,
                                                  unsigned* __restrict__ sl,
                                                  int* __restrict__ sel_flat,
                                                  float* __restrict__ sel_val,
                                                  unsigned* __restrict__ row_cnt)
{
    unsigned R = sl[SL_NTIE];
    if (R > (unsigned)TIE_CAP) R = (unsigned)TIE_CAP;
    const unsigned REM = sl[SL_S0 + 6];
    const unsigned D = sl[SL_DEF];
    const int c = blockIdx.x * blockDim.x + threadIdx.x;
    if (c >= (int)R) return;
    const int ic = tie_flat[c];
    unsigned rank = 0;
    for (int j = 0; j < (int)R; ++j)
        if (tie_flat[j] < ic) ++rank;
    if (rank < REM) {
        unsigned p = D + atomicAdd(&sl[SL_WIN], 1u);
        if (p < (unsigned)KB_SEL) {
            sel_flat[p] = ic;
            sel_val[p]  = (float)__longlong_as_double((long long)tie_key[c]);
            atomicAdd(&row_cnt[ic >> 14], 1u);
        }
    }
}

// ===========================================================================
// Row prefix sum
// ===========================================================================
__global__ __launch_bounds__(256) void sae16_scan(const unsigned* __restrict__ row_cnt,
                                                  unsigned* __restrict__ row_ofs)
{
    __shared__ unsigned s[256];
    const int t = threadIdx.x;
    unsigned c[8];
    unsigned sum = 0;
#pragma unroll
    for (int j = 0; j < 8; ++j) { c[j] = row_cnt[t * 8 + j]; sum += c[j]; }
    s[t] = sum;
    __syncthreads();
    for (int off = 1; off < 256; off <<= 1) {
        unsigned v = (t >= off) ? s[t - off] : 0u;
        __syncthreads();
        s[t] += v;
        __syncthreads();
    }
    unsigned run = s[t] - sum;
#pragma unroll
    for (int j = 0; j < 8; ++j) { row_ofs[t * 8 + j] = run; run += c[j]; }
    if (t == 255) row_ofs[2048] = run;
}

// ===========================================================================
// Scatter into row-grouped arrays
// ===========================================================================
__global__ void sae16_scatter(const int* __restrict__ sel_flat,
                              const float* __restrict__ sel_val,
                              const unsigned* __restrict__ row_ofs,
                              unsigned* __restrict__ cursor,
                              int* __restrict__ gf, float* __restrict__ gv)
{
    int e = blockIdx.x * blockDim.x + threadIdx.x;
    if (e >= KB_SEL) return;
    int flat = sel_flat[e];
    int b = flat >> 14;
    unsigned p = atomicAdd(&cursor[b], 1u);
    unsigned dst = row_ofs[b] + p;
    if (dst < (unsigned)KB_SEL) {
        gf[dst] = flat & (FEAT - 1);
        gv[dst] = sel_val[e];
    }
}

// ===========================================================================
// Sparse decode
// ===========================================================================
__global__ __launch_bounds__(256) void sae16_decode(const int* __restrict__ gf,
                                                    const float* __restrict__ gv,
                                                    const unsigned* __restrict__ row_ofs,
                                                    const float* __restrict__ Wt,
                                                    const float* __restrict__ bdec,
                                                    float* __restrict__ out)
{
    const int b = blockIdx.x;
    const int t = threadIdx.x;
    float a0 = 0.f, a1 = 0.f, a2 = 0.f;
    const unsigned s = row_ofs[b];
    const unsigned e = row_ofs[b + 1];
    for (unsigned i = s; i < e; ++i) {
        const int f   = gf[i];
        const float v = gv[i];
        const float* w = Wt + (size_t)f * DIM;
        a0 = fmaf(v, w[t], a0);
        a1 = fmaf(v, w[t + 256], a1);
        a2 = fmaf(v, w[t + 512], a2);
    }
    out[(size_t)b * DIM + t]       = a0 + bdec[t];
    out[(size_t)b * DIM + t + 256] = a1 + bdec[t + 256];
    out[(size_t)b * DIM + t + 512] = a2 + bdec[t + 512];
}

// ===========================================================================
extern "C" void kernel_launch(void* const* d_in, const int* in_sizes, int n_in,
                              void* d_out, int out_size, void* d_ws, size_t ws_size,
                              hipStream_t stream)
{
    (void)in_sizes; (void)n_in; (void)out_size;
    const float* x    = (const float*)d_in[0];
    const float* Wenc = (const float*)d_in[1];
    const float* benc = (const float*)d_in[2];
    const float* Wdec = (const float*)d_in[3];
    const float* bdec = (const float*)d_in[4];
    float* out = (float*)d_out;

    char* ws = (char*)d_ws;
    size_t off = 0;
    unsigned short* Yb  = (unsigned short*)(ws + off);     off += (size_t)N_TOT * 2;
    float*    Wt        = (float*)(ws + off);              off += (size_t)FEAT * DIM * 4;
    unsigned short* xb  = (unsigned short*)(ws + off);     off += (size_t)BATCH * DIM * 2;
    unsigned short* wb  = (unsigned short*)(ws + off);     off += (size_t)FEAT * DIM * 2;
    u64*      cand_key  = (u64*)(ws + off);                off += (size_t)CCAP * 8;
    int*      cand_raw  = (int*)(ws + off);                off += (size_t)CCAP * 4;
    int*      cand_flat = (int*)(ws + off);                off += (size_t)CCAP * 4;
    int*      tie_flat  = (int*)(ws + off);                off += (size_t)TIE_CAP * 4;
    u64*      tie_key   = (u64*)(ws + off);                off += (size_t)TIE_CAP * 8;
    unsigned* row_ofs   = (unsigned*)(ws + off);           off += 2052 * 4;
    unsigned* fofs      = (unsigned*)(ws + off);           off += 16384 * 4;
    // ---- contiguous ZERO ZONE (single memset) ----
    char* zstart = ws + off;
    int*      sel_flat  = (int*)(ws + off);                off += (size_t)KB_SEL * 4;
    float*    sel_val   = (float*)(ws + off);              off += (size_t)KB_SEL * 4;
    int*      gf        = (int*)(ws + off);                off += (size_t)KB_SEL * 4;
    float*    gv        = (float*)(ws + off);              off += (size_t)KB_SEL * 4;
    unsigned* hist1     = (unsigned*)(ws + off);           off += 16384 * 4;
    unsigned* h64       = (unsigned*)(ws + off);           off += 3 * 16384 * 4;
    unsigned* fhist     = (unsigned*)(ws + off);           off += 16384 * 4;
    unsigned* fcur      = (unsigned*)(ws + off);           off += 16384 * 4;
    unsigned* row_cnt   = (unsigned*)(ws + off);           off += 2048 * 4;
    unsigned* cursor    = (unsigned*)(ws + off);           off += 2048 * 4;
    u64*      mx        = (u64*)(ws + off);                off += 8;
    unsigned* sl        = (unsigned*)(ws + off);           off += 256;
    const size_t zbytes = (size_t)((ws + off) - zstart);
    if (ws_size < off) return;

    hipMemsetAsync(zstart, 0, zbytes, stream);

    // pre-convert + decoder transpose + encode GEMM
    sae16_prep<<<4096, 256, 0, stream>>>(x, Wenc, bdec, xb, wb);
    sae16_wt<<<dim3(FEAT / 32, DIM / 32), dim3(32, 8), 0, stream>>>(Wdec, Wt);
    sae16_gemm<<<dim3(FEAT / GBN, BATCH / GBM), 256, 0, stream>>>(xb, wb, benc, Yb);

    // prune threshold (one pass over bf16 Y)
    sae16_hist<<<512, 1024, 0, stream>>>(Yb, hist1);
    sae16_selb<<<1, 1024, 0, stream>>>(hist1, sl);

    // candidates -> feature-major reorder -> exact f64 keys
    sae16_cand<<<2048, 256, 0, stream>>>(Yb, sl, cand_raw);
    sae16_fhist<<<256, 256, 0, stream>>>(cand_raw, sl, fhist);
    sae16_fscan<<<1, 1024, 0, stream>>>(fhist, fofs);
    sae16_fscat<<<256, 256, 0, stream>>>(cand_raw, sl, fofs, fcur, cand_flat);
    sae16_feval<<<FBLK, 256, 0, stream>>>(x, Wenc, benc, bdec, sl, cand_flat, cand_key);

    // rank-K 42-bit prefix (3 passes) + rank-(K+1) via max-below
    for (int p = 0; p < 3; ++p) {
        sae16_hist64<<<256, 256, 0, stream>>>(cand_key, sl, h64 + p * 16384, p);
        sae16_sel14<<<1, 1024, 0, stream>>>(h64 + p * 16384, sl, p);
    }
    sae16_maxb<<<256, 256, 0, stream>>>(cand_key, sl, mx);

    // selection with rank-K <-> rank-(K+1) boundary swap
    sae16_class<<<(CCAP + 255) / 256, 256, 0, stream>>>(cand_key, cand_flat, mx, sl, row_cnt,
                                                        sel_flat, sel_val, tie_flat, tie_key);
    sae16_ties<<<TIE_CAP / 256, 256, 0, stream>>>(tie_flat, tie_key, sl,
                                                  sel_flat, sel_val, row_cnt);

    // group by batch row and decode sparsely
    sae16_scan<<<1, 256, 0, stream>>>(row_cnt, row_ofs);
    sae16_scatter<<<(KB_SEL + 255) / 256, 256, 0, stream>>>(sel_flat, sel_val, row_ofs, cursor, gf, gv);
    sae16_decode<<<BATCH, 256, 0, stream>>>(gf, gv, row_ofs, Wt, bdec, out);
}

// Round 21
// 449.124 us; speedup vs baseline: 1.1216x; 1.0304x over previous
//
#include <hip/hip_runtime.h>
#include <stdint.h>

// Problem constants
#define BATCH   2048
#define DIM     768
#define FEAT    16384
#define KSEL    64
#define KB_SEL  (BATCH * KSEL)      // 131072 selected
#define N_TOT   (BATCH * FEAT)      // 33554432
#define NX4     (BATCH * DIM / 4)
#define NW4     (FEAT * DIM / 4)

// MFMA GEMM tiling
#define GBM 128
#define GBN 128
#define GBK 32
#define AROW   24
#define APLANE 3088

// Sampled prune threshold (round-21): 1/64 deterministic sample, target
// sample-rank 3072 (= full-rank ~196608). Rank error ±25K (7 sigma) +
// bucket granularity (4 bf16-ulps ~ +31K) -> NC in [171K, 253K].
// Needs: NC >= KB_SEL + 2*bf16-err-band (~145K)  [min 171K OK]
//        NC <= CCAP                               [253K < 262144 OK]
#define SAMP_N  3072
#define CCAP    262144
#define TIE_CAP 1024
#define LSTAGE  2048
#define FG      8
#define FBLK    (CCAP / (FG * 4))   // 8192 blocks, %8==0 -> bijective swizzle

// scalar slots
#define SL_T32    0
#define SL_NC     1
#define SL_DEF    2
#define SL_NTIE   3
#define SL_WIN    4
#define SL_S0     16

typedef __attribute__((ext_vector_type(8))) __bf16 bf16x8;
typedef __attribute__((ext_vector_type(4))) float  f32x4;
typedef unsigned long long u64;

__device__ __forceinline__ unsigned short bf16r(float v)
{
    unsigned u = __float_as_uint(v);
    u += 0x7FFFu + ((u >> 16) & 1u);
    return (unsigned short)(u >> 16);
}

__device__ __forceinline__ unsigned wave_append(unsigned* counter, bool pred)
{
    unsigned long long m = __ballot(pred);
    if (m == 0ull) return 0xFFFFFFFFu;
    const int lane = threadIdx.x & 63;
    const int leader = __ffsll((unsigned long long)m) - 1;
    unsigned base = 0;
    if (lane == leader) base = atomicAdd(counter, (unsigned)__popcll(m));
    base = __shfl(base, leader, 64);
    if (!pred) return 0xFFFFFFFFu;
    return base + (unsigned)__popcll(m & ((1ull << lane) - 1ull));
}

// ===========================================================================
// Pre-convert: xb = bf16(x - bdec), wb = bf16(Wenc), once
// ===========================================================================
__global__ __launch_bounds__(256) void sae17_prep(const float* __restrict__ x,
                                                  const float* __restrict__ Wenc,
                                                  const float* __restrict__ bdec,
                                                  unsigned short* __restrict__ xb,
                                                  unsigned short* __restrict__ wb)
{
    const int tot = NX4 + NW4;
    for (int i = blockIdx.x * 256 + threadIdx.x; i < tot; i += gridDim.x * 256) {
        if (i < NX4) {
            const int e = i * 4;
            const int d = e % DIM;
            float4 v  = *(const float4*)(x + e);
            float4 dv = *(const float4*)(bdec + d);
            uint2 p;
            p.x = (unsigned)bf16r(v.x - dv.x) | ((unsigned)bf16r(v.y - dv.y) << 16);
            p.y = (unsigned)bf16r(v.z - dv.z) | ((unsigned)bf16r(v.w - dv.w) << 16);
            *(uint2*)(xb + e) = p;
        } else {
            const int e = (i - NX4) * 4;
            float4 v = *(const float4*)(Wenc + e);
            uint2 p;
            p.x = (unsigned)bf16r(v.x) | ((unsigned)bf16r(v.y) << 16);
            p.y = (unsigned)bf16r(v.z) | ((unsigned)bf16r(v.w) << 16);
            *(uint2*)(wb + e) = p;
        }
    }
}

// ===========================================================================
// Encode GEMM — bf16 MFMA, bf16 Y
// ===========================================================================
__global__ __launch_bounds__(256) void sae17_gemm(const unsigned short* __restrict__ xb,
                                                  const unsigned short* __restrict__ wb,
                                                  const float* __restrict__ benc,
                                                  unsigned short* __restrict__ Yb)
{
    __shared__ unsigned short Als[4 * APLANE];
    __shared__ unsigned short Bls[4 * APLANE];

    const int tid  = threadIdx.x;
    const int row0 = blockIdx.y * GBM;
    const int col0 = blockIdx.x * GBN;
    const int wid  = tid >> 6;
    const int lane = tid & 63;
    const int wr = wid >> 1;
    const int wc = wid & 1;
    const int fr = lane & 15;
    const int kg = lane >> 4;

    f32x4 acc[4][4];
#pragma unroll
    for (int i = 0; i < 4; ++i)
#pragma unroll
        for (int j = 0; j < 4; ++j) acc[i][j] = (f32x4){0.f, 0.f, 0.f, 0.f};

    for (int kt = 0; kt < DIM; kt += GBK) {
#pragma unroll
        for (int i = 0; i < 4; ++i) {
            const int idx = i * 256 + tid;
            const int r   = idx >> 3;
            const int kq  = (idx & 7) * 4;
            const int g   = kq >> 3;
            const int k0  = kq & 7;
            *(uint2*)&Als[g * APLANE + r * AROW + k0] =
                *(const uint2*)(xb + (size_t)(row0 + r) * DIM + kt + kq);
            *(uint2*)&Bls[g * APLANE + r * AROW + k0] =
                *(const uint2*)(wb + (size_t)(col0 + r) * DIM + kt + kq);
        }
        __syncthreads();

        bf16x8 afr[4], bfr[4];
#pragma unroll
        for (int mi = 0; mi < 4; ++mi)
            afr[mi] = *(const bf16x8*)&Als[kg * APLANE + (wr * 64 + mi * 16 + fr) * AROW];
#pragma unroll
        for (int ni = 0; ni < 4; ++ni)
            bfr[ni] = *(const bf16x8*)&Bls[kg * APLANE + (wc * 64 + ni * 16 + fr) * AROW];
#pragma unroll
        for (int mi = 0; mi < 4; ++mi)
#pragma unroll
            for (int ni = 0; ni < 4; ++ni)
                acc[mi][ni] = __builtin_amdgcn_mfma_f32_16x16x32_bf16(
                    afr[mi], bfr[ni], acc[mi][ni], 0, 0, 0);
        __syncthreads();
    }

#pragma unroll
    for (int ni = 0; ni < 4; ++ni) {
        const int col = col0 + wc * 64 + ni * 16 + fr;
        const float be = benc[col];
#pragma unroll
        for (int mi = 0; mi < 4; ++mi) {
            const int rbase = row0 + wr * 64 + mi * 16 + kg * 4;
#pragma unroll
            for (int j = 0; j < 4; ++j)
                Yb[(size_t)(rbase + j) * FEAT + col] =
                    bf16r(fmaxf(acc[mi][ni][j] + be, 0.f));
        }
    }
}

// ===========================================================================
// W_dec transpose -> bf16 (round-21: halves wt write + decode fetch;
// comparison is on a bf16-value grid with 10x threshold headroom)
// ===========================================================================
__global__ void sae17_wt(const float* __restrict__ Wdec,
                         unsigned short* __restrict__ Wtb)
{
    __shared__ float t[32][33];
    const int f0 = blockIdx.x * 32;
    const int d0 = blockIdx.y * 32;
    const int tx = threadIdx.x;
    const int ty = threadIdx.y;
#pragma unroll
    for (int i = 0; i < 4; ++i)
        t[ty + i * 8][tx] = Wdec[(size_t)(d0 + ty + i * 8) * FEAT + f0 + tx];
    __syncthreads();
#pragma unroll
    for (int i = 0; i < 4; ++i)
        Wtb[(size_t)(f0 + ty + i * 8) * DIM + d0 + tx] = bf16r(t[tx][ty + i * 8]);
}

// ===========================================================================
// SAMPLED histogram (round-21): 1/64 deterministic sample of Y, 8192 bins
// (positive bf16 bits >>2). Replaces the full 67MB Y histogram pass.
// ===========================================================================
__global__ __launch_bounds__(256) void sae17_shist(const unsigned short* __restrict__ Yb,
                                                   unsigned* __restrict__ hist)
{
    __shared__ unsigned h[8192];
    const int t = threadIdx.x;
    for (int i = t; i < 8192; i += 256) h[i] = 0u;
    __syncthreads();
    const uint4* Y8 = (const uint4*)Yb;
    const int idx = blockIdx.x * 256 + t;        // 0..65535
    const int i = idx * 64;                      // every 64th uint4 block
    if (i < N_TOT / 8) {
        uint4 v = Y8[i];
        unsigned w[4] = {v.x, v.y, v.z, v.w};
#pragma unroll
        for (int k = 0; k < 4; ++k) {
            unsigned lo = w[k] & 0xFFFFu;
            unsigned hi = w[k] >> 16;
            if (lo) atomicAdd(&h[lo >> 2], 1u);
            if (hi) atomicAdd(&h[hi >> 2], 1u);
        }
    }
    __syncthreads();
    for (int i2 = t; i2 < 8192; i2 += 256) {
        unsigned c = h[i2];
        if (c) atomicAdd(&hist[i2], c);
    }
}

// ===========================================================================
// Prune-threshold select from sampled hist (target sample-rank SAMP_N)
// ===========================================================================
__global__ __launch_bounds__(1024) void sae17_selb(const unsigned* __restrict__ hist,
                                                   unsigned* sl)
{
    __shared__ unsigned s[1024];
    const int t = threadIdx.x;
    const int C = 8;
    const unsigned N = (unsigned)SAMP_N;
    const int lo = t * C;
    unsigned S = 0;
    for (int i = 0; i < C; ++i) S += hist[lo + i];
    s[t] = S;
    __syncthreads();
    for (int off = 1; off < 1024; off <<= 1) {
        unsigned v = (t + off < 1024) ? s[t + off] : 0u;
        __syncthreads();
        s[t] += v;
        __syncthreads();
    }
    const unsigned incl  = s[t];
    const unsigned above = incl - S;
    if (above < N && N <= incl) {
        unsigned cum = above;
        for (int i = lo + C - 1; i >= lo; --i) {
            cum += hist[i];
            if (cum >= N) { sl[SL_T32] = (unsigned)i << 2; break; }
        }
    }
}

// ===========================================================================
// Candidate compact — BLOCK-STAGED
// ===========================================================================
__global__ __launch_bounds__(256) void sae17_cand(const unsigned short* __restrict__ Yb,
                                                  unsigned* __restrict__ sl,
                                                  int* __restrict__ cand_raw)
{
    __shared__ int      loc[LSTAGE];
    __shared__ unsigned lcnt;
    __shared__ unsigned gbase;
    if (threadIdx.x == 0) lcnt = 0;
    __syncthreads();

    const unsigned T = sl[SL_T32];
    const uint4* Y8 = (const uint4*)Yb;
    const int total8 = N_TOT / 8;
    for (int i = blockIdx.x * blockDim.x + threadIdx.x; i < total8;
         i += gridDim.x * blockDim.x) {
        uint4 v = Y8[i];
        unsigned w[4] = {v.x, v.y, v.z, v.w};
#pragma unroll
        for (int k = 0; k < 4; ++k) {
            unsigned lo = w[k] & 0xFFFFu;
            unsigned hi = w[k] >> 16;
            if (lo >= T) {
                unsigned p = atomicAdd(&lcnt, 1u);
                if (p < (unsigned)LSTAGE) loc[p] = i * 8 + k * 2;
            }
            if (hi >= T) {
                unsigned p = atomicAdd(&lcnt, 1u);
                if (p < (unsigned)LSTAGE) loc[p] = i * 8 + k * 2 + 1;
            }
        }
    }
    __syncthreads();
    unsigned n = lcnt;
    if (n > (unsigned)LSTAGE) n = (unsigned)LSTAGE;
    if (threadIdx.x == 0) gbase = atomicAdd(&sl[SL_NC], n);
    __syncthreads();
    const unsigned base = gbase;
    for (unsigned k = threadIdx.x; k < n; k += blockDim.x) {
        unsigned dst = base + k;
        if (dst < (unsigned)CCAP) cand_raw[dst] = loc[k];
    }
}

// ===========================================================================
// Feature-major candidate reorder (counting sort by feature id)
// ===========================================================================
__global__ __launch_bounds__(256) void sae17_fhist(const int* __restrict__ cand_raw,
                                                   const unsigned* __restrict__ sl,
                                                   unsigned* __restrict__ fhist)
{
    __shared__ unsigned h[16384];
    const int t = threadIdx.x;
    for (int i = t; i < 16384; i += 256) h[i] = 0u;
    __syncthreads();
    unsigned NC = sl[SL_NC];
    if (NC > (unsigned)CCAP) NC = (unsigned)CCAP;
    for (int i = blockIdx.x * 256 + t; i < (int)NC; i += gridDim.x * 256)
        atomicAdd(&h[cand_raw[i] & (FEAT - 1)], 1u);
    __syncthreads();
    for (int i = t; i < 16384; i += 256) {
        unsigned c = h[i];
        if (c) atomicAdd(&fhist[i], c);
    }
}

__global__ __launch_bounds__(1024) void sae17_fscan(const unsigned* __restrict__ fhist,
                                                    unsigned* __restrict__ fofs)
{
    __shared__ unsigned s[1024];
    const int t = threadIdx.x;
    unsigned c[16];
    unsigned sum = 0;
#pragma unroll
    for (int j = 0; j < 16; ++j) { c[j] = fhist[t * 16 + j]; sum += c[j]; }
    s[t] = sum;
    __syncthreads();
    for (int off = 1; off < 1024; off <<= 1) {
        unsigned v = (t >= off) ? s[t - off] : 0u;
        __syncthreads();
        s[t] += v;
        __syncthreads();
    }
    unsigned run = s[t] - sum;
#pragma unroll
    for (int j = 0; j < 16; ++j) { fofs[t * 16 + j] = run; run += c[j]; }
}

__global__ __launch_bounds__(256) void sae17_fscat(const int* __restrict__ cand_raw,
                                                   const unsigned* __restrict__ sl,
                                                   const unsigned* __restrict__ fofs,
                                                   unsigned* __restrict__ fcur,
                                                   int* __restrict__ cand_flat)
{
    unsigned NC = sl[SL_NC];
    if (NC > (unsigned)CCAP) NC = (unsigned)CCAP;
    for (int i = blockIdx.x * 256 + threadIdx.x; i < (int)NC; i += gridDim.x * 256) {
        int flat = cand_raw[i];
        int f = flat & (FEAT - 1);
        unsigned p = atomicAdd(&fcur[f], 1u);
        unsigned dst = fofs[f] + p;
        if (dst < (unsigned)CCAP) cand_flat[dst] = flat;
    }
}

// ===========================================================================
// f64 exact evaluation — FG candidates/wave, reg-cached Wenc row, XCD swizzle
// ===========================================================================
__global__ __launch_bounds__(256) void sae17_feval(const float* __restrict__ x,
                                                   const float* __restrict__ Wenc,
                                                   const float* __restrict__ benc,
                                                   const float* __restrict__ bdec,
                                                   const unsigned* __restrict__ sl,
                                                   const int* __restrict__ cand_flat,
                                                   u64* __restrict__ cand_key)
{
    unsigned NC = sl[SL_NC];
    if (NC > (unsigned)CCAP) NC = (unsigned)CCAP;
    const int lane = threadIdx.x & 63;
    const int b = blockIdx.x;
    const int lb = (b & 7) * (FBLK / 8) + (b >> 3);
    const int wid = lb * 4 + (threadIdx.x >> 6);
    const int c0 = wid * FG;
    if (c0 >= (int)NC) return;

    float bd[12], wv[12];
#pragma unroll
    for (int j = 0; j < 12; ++j) bd[j] = bdec[lane + j * 64];
    int fprev = -1;

    for (int g = 0; g < FG; ++g) {
        const int c = c0 + g;
        if (c >= (int)NC) break;
        const int flat = cand_flat[c];
        const int bb = flat >> 14;
        const int f  = flat & (FEAT - 1);
        if (f != fprev) {
            const float* wr = Wenc + (size_t)f * DIM;
#pragma unroll
            for (int j = 0; j < 12; ++j) wv[j] = wr[lane + j * 64];
            fprev = f;
        }
        const float* xr = x + (size_t)bb * DIM;
        double p = 0.0;
#pragma unroll
        for (int j = 0; j < 12; ++j)
            p = fma((double)xr[lane + j * 64] - (double)bd[j], (double)wv[j], p);
#pragma unroll
        for (int o = 32; o > 0; o >>= 1) p += __shfl_xor(p, o, 64);
        if (lane == 0) {
            p += (double)benc[f];
            if (p < 0.0) p = 0.0;
            cand_key[c] = (u64)__double_as_longlong(p);
        }
    }
}

// ===========================================================================
// u64 radix histogram — 3 LDS-privatized 14-bit passes (42-bit prefix)
// ===========================================================================
__global__ __launch_bounds__(256) void sae17_hist64(const u64* __restrict__ cand_key,
                                                    const unsigned* __restrict__ sl,
                                                    unsigned* __restrict__ hist,
                                                    int pass)
{
    __shared__ unsigned h[16384];
    const int t = threadIdx.x;
    for (int i = t; i < 16384; i += 256) h[i] = 0u;
    __syncthreads();

    unsigned NC = sl[SL_NC];
    if (NC > (unsigned)CCAP) NC = (unsigned)CCAP;
    u64 pref = 0;
    for (int i = 0; i < pass; ++i) pref = (pref << 14) | (u64)sl[SL_S0 + i];
    const int chk_sh = 64 - 14 * pass;
    const int bkt_sh = 50 - 14 * pass;

    for (int i = blockIdx.x * 256 + t; i < (int)NC; i += gridDim.x * 256) {
        u64 key = cand_key[i];
        if (pass > 0 && (key >> chk_sh) != pref) continue;
        atomicAdd(&h[(unsigned)(key >> bkt_sh) & 0x3FFFu], 1u);
    }
    __syncthreads();
    for (int i = t; i < 16384; i += 256) {
        unsigned c = h[i];
        if (c) atomicAdd(&hist[i], c);
    }
}

// ===========================================================================
// 14-bit k-th select per radix pass (rank-K)
// ===========================================================================
__global__ __launch_bounds__(1024) void sae17_sel14(const unsigned* __restrict__ hist,
                                                    unsigned* sl, int pass)
{
    __shared__ unsigned s[1024];
    const int t = threadIdx.x;
    const int C = 16;
    const unsigned N = (pass == 0) ? (unsigned)KB_SEL : sl[SL_S0 + 4 + pass - 1];
    const int lo = t * C;
    unsigned S = 0;
    for (int i = 0; i < C; ++i) S += hist[lo + i];
    s[t] = S;
    __syncthreads();
    for (int off = 1; off < 1024; off <<= 1) {
        unsigned v = (t + off < 1024) ? s[t + off] : 0u;
        __syncthreads();
        s[t] += v;
        __syncthreads();
    }
    const unsigned incl  = s[t];
    const unsigned above = incl - S;
    if (above < N && N <= incl) {
        unsigned cum = above;
        for (int i = lo + C - 1; i >= lo; --i) {
            cum += hist[i];
            if (cum >= N) {
                sl[SL_S0 + pass]     = (unsigned)i;
                sl[SL_S0 + 4 + pass] = N - (cum - hist[i]);
                break;
            }
        }
    }
}

// ===========================================================================
// Max key strictly below rank-K prefix group == rank-(K+1) key
// ===========================================================================
__global__ __launch_bounds__(256) void sae17_maxb(const u64* __restrict__ cand_key,
                                                  const unsigned* __restrict__ sl,
                                                  u64* __restrict__ mx)
{
    unsigned NC = sl[SL_NC];
    if (NC > (unsigned)CCAP) NC = (unsigned)CCAP;
    const u64 Tsh1 = ((u64)sl[SL_S0 + 0] << 28) | ((u64)sl[SL_S0 + 1] << 14) |
                     (u64)sl[SL_S0 + 2];
    u64 m = 0;
    for (int i = blockIdx.x * 256 + threadIdx.x; i < (int)NC; i += gridDim.x * 256) {
        u64 k = cand_key[i];
        if ((k >> 22) < Tsh1 && k > m) m = k;
    }
#pragma unroll
    for (int o = 32; o > 0; o >>= 1) {
        u64 o2 = __shfl_xor(m, o, 64);
        if (o2 > m) m = o2;
    }
    if ((threadIdx.x & 63) == 0 && m) atomicMax((unsigned long long*)mx, m);
}

// ===========================================================================
// Final classify with BOUNDARY SWAP (42-bit prefixes)
// ===========================================================================
__global__ __launch_bounds__(256) void sae17_class(const u64* __restrict__ cand_key,
                                                   const int* __restrict__ cand_flat,
                                                   const u64* __restrict__ mx,
                                                   unsigned* __restrict__ sl,
                                                   unsigned* __restrict__ row_cnt,
                                                   int* __restrict__ sel_flat,
                                                   float* __restrict__ sel_val,
                                                   int* __restrict__ tie_flat,
                                                   u64* __restrict__ tie_key)
{
    unsigned NC = sl[SL_NC];
    if (NC > (unsigned)CCAP) NC = (unsigned)CCAP;
    const u64 Tsh1 = ((u64)sl[SL_S0 + 0] << 28) | ((u64)sl[SL_S0 + 1] << 14) |
                     (u64)sl[SL_S0 + 2];
    const u64 Tsh2 = mx[0] >> 22;
    const int c = blockIdx.x * 256 + threadIdx.x;
    const bool active = (c < (int)NC);
    u64 key = 0;
    int flat = 0;
    u64 keysh = 0;
    if (active) {
        key = cand_key[c];
        keysh = key >> 22;
        flat = cand_flat[c];
    }
    const bool selp = active && (keysh > Tsh1);
    unsigned p = wave_append(&sl[SL_DEF], selp);
    if (selp && p < (unsigned)KB_SEL) {
        sel_flat[p] = flat;
        sel_val[p]  = (float)__longlong_as_double((long long)key);
        atomicAdd(&row_cnt[flat >> 14], 1u);
    }
    const bool tiep = active && !selp && (keysh == Tsh2);
    unsigned q = wave_append(&sl[SL_NTIE], tiep);
    if (tiep && q < (unsigned)TIE_CAP) { tie_flat[q] = flat; tie_key[q] = key; }
}

// ===========================================================================
// Tie/swap resolve: REM lowest flat indices
// ===========================================================================
__global__ __launch_bounds__(256) void sae17_ties(const int* __restrict__ tie_flat,
                                                  const u64* __restrict__ tie_key,
                                                  unsigned* __restrict__ sl,
                                                  int* __restrict__ sel_flat,
                                                  float* __restrict__ sel_val,
                                                  unsigned* __restrict__ row_cnt)
{
    unsigned R = sl[SL_NTIE];
    if (R > (unsigned)TIE_CAP) R = (unsigned)TIE_CAP;
    const unsigned REM = sl[SL_S0 + 6];
    const unsigned D = sl[SL_DEF];
    const int c = blockIdx.x * blockDim.x + threadIdx.x;
    if (c >= (int)R) return;
    const int ic = tie_flat[c];
    unsigned rank = 0;
    for (int j = 0; j < (int)R; ++j)
        if (tie_flat[j] < ic) ++rank;
    if (rank < REM) {
        unsigned p = D + atomicAdd(&sl[SL_WIN], 1u);
        if (p < (unsigned)KB_SEL) {
            sel_flat[p] = ic;
            sel_val[p]  = (float)__longlong_as_double((long long)tie_key[c]);
            atomicAdd(&row_cnt[ic >> 14], 1u);
        }
    }
}

// ===========================================================================
// Row prefix sum
// ===========================================================================
__global__ __launch_bounds__(256) void sae17_scan(const unsigned* __restrict__ row_cnt,
                                                  unsigned* __restrict__ row_ofs)
{
    __shared__ unsigned s[256];
    const int t = threadIdx.x;
    unsigned c[8];
    unsigned sum = 0;
#pragma unroll
    for (int j = 0; j < 8; ++j) { c[j] = row_cnt[t * 8 + j]; sum += c[j]; }
    s[t] = sum;
    __syncthreads();
    for (int off = 1; off < 256; off <<= 1) {
        unsigned v = (t >= off) ? s[t - off] : 0u;
        __syncthreads();
        s[t] += v;
        __syncthreads();
    }
    unsigned run = s[t] - sum;
#pragma unroll
    for (int j = 0; j < 8; ++j) { row_ofs[t * 8 + j] = run; run += c[j]; }
    if (t == 255) row_ofs[2048] = run;
}

// ===========================================================================
// Scatter into row-grouped arrays
// ===========================================================================
__global__ void sae17_scatter(const int* __restrict__ sel_flat,
                              const float* __restrict__ sel_val,
                              const unsigned* __restrict__ row_ofs,
                              unsigned* __restrict__ cursor,
                              int* __restrict__ gf, float* __restrict__ gv)
{
    int e = blockIdx.x * blockDim.x + threadIdx.x;
    if (e >= KB_SEL) return;
    int flat = sel_flat[e];
    int b = flat >> 14;
    unsigned p = atomicAdd(&cursor[b], 1u);
    unsigned dst = row_ofs[b] + p;
    if (dst < (unsigned)KB_SEL) {
        gf[dst] = flat & (FEAT - 1);
        gv[dst] = sel_val[e];
    }
}

// ===========================================================================
// Sparse decode — reads bf16 Wt
// ===========================================================================
__global__ __launch_bounds__(256) void sae17_decode(const int* __restrict__ gf,
                                                    const float* __restrict__ gv,
                                                    const unsigned* __restrict__ row_ofs,
                                                    const unsigned short* __restrict__ Wtb,
                                                    const float* __restrict__ bdec,
                                                    float* __restrict__ out)
{
    const int b = blockIdx.x;
    const int t = threadIdx.x;
    float a0 = 0.f, a1 = 0.f, a2 = 0.f;
    const unsigned s = row_ofs[b];
    const unsigned e = row_ofs[b + 1];
    for (unsigned i = s; i < e; ++i) {
        const int f   = gf[i];
        const float v = gv[i];
        const unsigned short* w = Wtb + (size_t)f * DIM;
        a0 = fmaf(v, __uint_as_float((unsigned)w[t]       << 16), a0);
        a1 = fmaf(v, __uint_as_float((unsigned)w[t + 256] << 16), a1);
        a2 = fmaf(v, __uint_as_float((unsigned)w[t + 512] << 16), a2);
    }
    out[(size_t)b * DIM + t]       = a0 + bdec[t];
    out[(size_t)b * DIM + t + 256] = a1 + bdec[t + 256];
    out[(size_t)b * DIM + t + 512] = a2 + bdec[t + 512];
}

// ===========================================================================
extern "C" void kernel_launch(void* const* d_in, const int* in_sizes, int n_in,
                              void* d_out, int out_size, void* d_ws, size_t ws_size,
                              hipStream_t stream)
{
    (void)in_sizes; (void)n_in; (void)out_size;
    const float* x    = (const float*)d_in[0];
    const float* Wenc = (const float*)d_in[1];
    const float* benc = (const float*)d_in[2];
    const float* Wdec = (const float*)d_in[3];
    const float* bdec = (const float*)d_in[4];
    float* out = (float*)d_out;

    char* ws = (char*)d_ws;
    size_t off = 0;
    unsigned short* Yb  = (unsigned short*)(ws + off);     off += (size_t)N_TOT * 2;
    unsigned short* Wtb = (unsigned short*)(ws + off);     off += (size_t)FEAT * DIM * 2;
    unsigned short* xb  = (unsigned short*)(ws + off);     off += (size_t)BATCH * DIM * 2;
    unsigned short* wb  = (unsigned short*)(ws + off);     off += (size_t)FEAT * DIM * 2;
    u64*      cand_key  = (u64*)(ws + off);                off += (size_t)CCAP * 8;
    int*      cand_raw  = (int*)(ws + off);                off += (size_t)CCAP * 4;
    int*      cand_flat = (int*)(ws + off);                off += (size_t)CCAP * 4;
    int*      tie_flat  = (int*)(ws + off);                off += (size_t)TIE_CAP * 4;
    u64*      tie_key   = (u64*)(ws + off);                off += (size_t)TIE_CAP * 8;
    unsigned* row_ofs   = (unsigned*)(ws + off);           off += 2052 * 4;
    unsigned* fofs      = (unsigned*)(ws + off);           off += 16384 * 4;
    // ---- contiguous ZERO ZONE (single memset) ----
    char* zstart = ws + off;
    int*      sel_flat  = (int*)(ws + off);                off += (size_t)KB_SEL * 4;
    float*    sel_val   = (float*)(ws + off);              off += (size_t)KB_SEL * 4;
    int*      gf        = (int*)(ws + off);                off += (size_t)KB_SEL * 4;
    float*    gv        = (float*)(ws + off);              off += (size_t)KB_SEL * 4;
    unsigned* hist1     = (unsigned*)(ws + off);           off += 8192 * 4;
    unsigned* h64       = (unsigned*)(ws + off);           off += 3 * 16384 * 4;
    unsigned* fhist     = (unsigned*)(ws + off);           off += 16384 * 4;
    unsigned* fcur      = (unsigned*)(ws + off);           off += 16384 * 4;
    unsigned* row_cnt   = (unsigned*)(ws + off);           off += 2048 * 4;
    unsigned* cursor    = (unsigned*)(ws + off);           off += 2048 * 4;
    u64*      mx        = (u64*)(ws + off);                off += 8;
    unsigned* sl        = (unsigned*)(ws + off);           off += 256;
    const size_t zbytes = (size_t)((ws + off) - zstart);
    if (ws_size < off) return;

    hipMemsetAsync(zstart, 0, zbytes, stream);

    // pre-convert + decoder transpose (bf16) + encode GEMM
    sae17_prep<<<4096, 256, 0, stream>>>(x, Wenc, bdec, xb, wb);
    sae17_wt<<<dim3(FEAT / 32, DIM / 32), dim3(32, 8), 0, stream>>>(Wdec, Wtb);
    sae17_gemm<<<dim3(FEAT / GBN, BATCH / GBM), 256, 0, stream>>>(xb, wb, benc, Yb);

    // sampled prune threshold (1/64 of Y)
    sae17_shist<<<256, 256, 0, stream>>>(Yb, hist1);
    sae17_selb<<<1, 1024, 0, stream>>>(hist1, sl);

    // candidates -> feature-major reorder -> exact f64 keys
    sae17_cand<<<2048, 256, 0, stream>>>(Yb, sl, cand_raw);
    sae17_fhist<<<256, 256, 0, stream>>>(cand_raw, sl, fhist);
    sae17_fscan<<<1, 1024, 0, stream>>>(fhist, fofs);
    sae17_fscat<<<256, 256, 0, stream>>>(cand_raw, sl, fofs, fcur, cand_flat);
    sae17_feval<<<FBLK, 256, 0, stream>>>(x, Wenc, benc, bdec, sl, cand_flat, cand_key);

    // rank-K 42-bit prefix (3 passes) + rank-(K+1) via max-below
    for (int p = 0; p < 3; ++p) {
        sae17_hist64<<<256, 256, 0, stream>>>(cand_key, sl, h64 + p * 16384, p);
        sae17_sel14<<<1, 1024, 0, stream>>>(h64 + p * 16384, sl, p);
    }
    sae17_maxb<<<256, 256, 0, stream>>>(cand_key, sl, mx);

    // selection with rank-K <-> rank-(K+1) boundary swap
    sae17_class<<<(CCAP + 255) / 256, 256, 0, stream>>>(cand_key, cand_flat, mx, sl, row_cnt,
                                                        sel_flat, sel_val, tie_flat, tie_key);
    sae17_ties<<<TIE_CAP / 256, 256, 0, stream>>>(tie_flat, tie_key, sl,
                                                  sel_flat, sel_val, row_cnt);

    // group by batch row and decode sparsely (bf16 Wt)
    sae17_scan<<<1, 256, 0, stream>>>(row_cnt, row_ofs);
    sae17_scatter<<<(KB_SEL + 255) / 256, 256, 0, stream>>>(sel_flat, sel_val, row_ofs, cursor, gf, gv);
    sae17_decode<<<BATCH, 256, 0, stream>>>(gf, gv, row_ofs, Wtb, bdec, out);
}

// Round 22
// 434.671 us; speedup vs baseline: 1.1589x; 1.0332x over previous
//
#include <hip/hip_runtime.h>
#include <stdint.h>

// Problem constants
#define BATCH   2048
#define DIM     768
#define FEAT    16384
#define KSEL    64
#define KB_SEL  (BATCH * KSEL)      // 131072 selected
#define N_TOT   (BATCH * FEAT)      // 33554432
#define NX4     (BATCH * DIM / 4)
#define NW4     (FEAT * DIM / 4)

// MFMA GEMM tiling
#define GBM 128
#define GBN 128
#define GBK 32
#define AROW   24
#define APLANE 3088

// Round-22: threshold from a 128-row SAMPLE GEMM (1/16 of rows), then the
// main GEMM appends candidates inline — Y is never materialized.
// Sample-rank 12288 = full-rank ~196608; NC in [184K, 239K] (7 sigma +
// bucket granularity), within [145K needed, CCAP].
#define SAMP_ROWS 128
#define SAMP_N    12288
#define CCAP      262144
#define TIE_CAP   1024
#define LSTAGE    2048
#define FG        8
#define FBLK      (CCAP / (FG * 4))  // 8192 blocks, %8==0 -> bijective swizzle

// scalar slots
#define SL_T32    0
#define SL_NC     1
#define SL_DEF    2
#define SL_NTIE   3
#define SL_WIN    4
#define SL_S0     16

typedef __attribute__((ext_vector_type(8))) __bf16 bf16x8;
typedef __attribute__((ext_vector_type(4))) float  f32x4;
typedef unsigned long long u64;

__device__ __forceinline__ unsigned short bf16r(float v)
{
    unsigned u = __float_as_uint(v);
    u += 0x7FFFu + ((u >> 16) & 1u);
    return (unsigned short)(u >> 16);
}

__device__ __forceinline__ unsigned wave_append(unsigned* counter, bool pred)
{
    unsigned long long m = __ballot(pred);
    if (m == 0ull) return 0xFFFFFFFFu;
    const int lane = threadIdx.x & 63;
    const int leader = __ffsll((unsigned long long)m) - 1;
    unsigned base = 0;
    if (lane == leader) base = atomicAdd(counter, (unsigned)__popcll(m));
    base = __shfl(base, leader, 64);
    if (!pred) return 0xFFFFFFFFu;
    return base + (unsigned)__popcll(m & ((1ull << lane) - 1ull));
}

// ===========================================================================
// Pre-convert: xb = bf16(x - bdec), wb = bf16(Wenc), once
// ===========================================================================
__global__ __launch_bounds__(256) void sae18_prep(const float* __restrict__ x,
                                                  const float* __restrict__ Wenc,
                                                  const float* __restrict__ bdec,
                                                  unsigned short* __restrict__ xb,
                                                  unsigned short* __restrict__ wb)
{
    const int tot = NX4 + NW4;
    for (int i = blockIdx.x * 256 + threadIdx.x; i < tot; i += gridDim.x * 256) {
        if (i < NX4) {
            const int e = i * 4;
            const int d = e % DIM;
            float4 v  = *(const float4*)(x + e);
            float4 dv = *(const float4*)(bdec + d);
            uint2 p;
            p.x = (unsigned)bf16r(v.x - dv.x) | ((unsigned)bf16r(v.y - dv.y) << 16);
            p.y = (unsigned)bf16r(v.z - dv.z) | ((unsigned)bf16r(v.w - dv.w) << 16);
            *(uint2*)(xb + e) = p;
        } else {
            const int e = (i - NX4) * 4;
            float4 v = *(const float4*)(Wenc + e);
            uint2 p;
            p.x = (unsigned)bf16r(v.x) | ((unsigned)bf16r(v.y) << 16);
            p.y = (unsigned)bf16r(v.z) | ((unsigned)bf16r(v.w) << 16);
            *(uint2*)(wb + e) = p;
        }
    }
}

// ===========================================================================
// SAMPLE GEMM (rows 0..127): same math as main GEMM; epilogue histograms
// the bf16 bits into 8192 LDS bins (no Y written anywhere).
// ===========================================================================
__global__ __launch_bounds__(256) void sae18_sgemm(const unsigned short* __restrict__ xb,
                                                   const unsigned short* __restrict__ wb,
                                                   const float* __restrict__ benc,
                                                   unsigned* __restrict__ hist)
{
    __shared__ unsigned short Als[4 * APLANE];
    __shared__ unsigned short Bls[4 * APLANE];
    __shared__ unsigned h[8192];

    const int tid  = threadIdx.x;
    for (int i = tid; i < 8192; i += 256) h[i] = 0u;
    const int row0 = 0;
    const int col0 = blockIdx.x * GBN;
    const int wid  = tid >> 6;
    const int lane = tid & 63;
    const int wr = wid >> 1;
    const int wc = wid & 1;
    const int fr = lane & 15;
    const int kg = lane >> 4;

    f32x4 acc[4][4];
#pragma unroll
    for (int i = 0; i < 4; ++i)
#pragma unroll
        for (int j = 0; j < 4; ++j) acc[i][j] = (f32x4){0.f, 0.f, 0.f, 0.f};

    for (int kt = 0; kt < DIM; kt += GBK) {
#pragma unroll
        for (int i = 0; i < 4; ++i) {
            const int idx = i * 256 + tid;
            const int r   = idx >> 3;
            const int kq  = (idx & 7) * 4;
            const int g   = kq >> 3;
            const int k0  = kq & 7;
            *(uint2*)&Als[g * APLANE + r * AROW + k0] =
                *(const uint2*)(xb + (size_t)(row0 + r) * DIM + kt + kq);
            *(uint2*)&Bls[g * APLANE + r * AROW + k0] =
                *(const uint2*)(wb + (size_t)(col0 + r) * DIM + kt + kq);
        }
        __syncthreads();

        bf16x8 afr[4], bfr[4];
#pragma unroll
        for (int mi = 0; mi < 4; ++mi)
            afr[mi] = *(const bf16x8*)&Als[kg * APLANE + (wr * 64 + mi * 16 + fr) * AROW];
#pragma unroll
        for (int ni = 0; ni < 4; ++ni)
            bfr[ni] = *(const bf16x8*)&Bls[kg * APLANE + (wc * 64 + ni * 16 + fr) * AROW];
#pragma unroll
        for (int mi = 0; mi < 4; ++mi)
#pragma unroll
            for (int ni = 0; ni < 4; ++ni)
                acc[mi][ni] = __builtin_amdgcn_mfma_f32_16x16x32_bf16(
                    afr[mi], bfr[ni], acc[mi][ni], 0, 0, 0);
        __syncthreads();
    }

#pragma unroll
    for (int ni = 0; ni < 4; ++ni) {
        const int col = col0 + wc * 64 + ni * 16 + fr;
        const float be = benc[col];
#pragma unroll
        for (int mi = 0; mi < 4; ++mi) {
#pragma unroll
            for (int j = 0; j < 4; ++j) {
                unsigned short bits = bf16r(fmaxf(acc[mi][ni][j] + be, 0.f));
                if (bits) atomicAdd(&h[bits >> 2], 1u);
            }
        }
    }
    __syncthreads();
    for (int i = tid; i < 8192; i += 256) {
        unsigned c = h[i];
        if (c) atomicAdd(&hist[i], c);
    }
}

// ===========================================================================
// Prune-threshold select from sample hist (target sample-rank SAMP_N)
// ===========================================================================
__global__ __launch_bounds__(1024) void sae18_selb(const unsigned* __restrict__ hist,
                                                   unsigned* sl)
{
    __shared__ unsigned s[1024];
    const int t = threadIdx.x;
    const int C = 8;
    const unsigned N = (unsigned)SAMP_N;
    const int lo = t * C;
    unsigned S = 0;
    for (int i = 0; i < C; ++i) S += hist[lo + i];
    s[t] = S;
    __syncthreads();
    for (int off = 1; off < 1024; off <<= 1) {
        unsigned v = (t + off < 1024) ? s[t + off] : 0u;
        __syncthreads();
        s[t] += v;
        __syncthreads();
    }
    const unsigned incl  = s[t];
    const unsigned above = incl - S;
    if (above < N && N <= incl) {
        unsigned cum = above;
        for (int i = lo + C - 1; i >= lo; --i) {
            cum += hist[i];
            if (cum >= N) { sl[SL_T32] = (unsigned)i << 2; break; }
        }
    }
}

// ===========================================================================
// MAIN GEMM — bf16 MFMA; epilogue appends candidates inline (NO Y output).
// bits >= T (bucket lower bound) -> block-staged candidate list, one global
// atomic per block (round-13 pattern). Same superset semantics as before.
// ===========================================================================
__global__ __launch_bounds__(256) void sae18_gemm(const unsigned short* __restrict__ xb,
                                                  const unsigned short* __restrict__ wb,
                                                  const float* __restrict__ benc,
                                                  unsigned* __restrict__ sl,
                                                  int* __restrict__ cand_raw)
{
    __shared__ unsigned short Als[4 * APLANE];
    __shared__ unsigned short Bls[4 * APLANE];
    __shared__ int      loc[LSTAGE];
    __shared__ unsigned lcnt;
    __shared__ unsigned gbase;

    const int tid  = threadIdx.x;
    if (tid == 0) lcnt = 0;
    const int row0 = blockIdx.y * GBM;
    const int col0 = blockIdx.x * GBN;
    const int wid  = tid >> 6;
    const int lane = tid & 63;
    const int wr = wid >> 1;
    const int wc = wid & 1;
    const int fr = lane & 15;
    const int kg = lane >> 4;

    f32x4 acc[4][4];
#pragma unroll
    for (int i = 0; i < 4; ++i)
#pragma unroll
        for (int j = 0; j < 4; ++j) acc[i][j] = (f32x4){0.f, 0.f, 0.f, 0.f};

    for (int kt = 0; kt < DIM; kt += GBK) {
#pragma unroll
        for (int i = 0; i < 4; ++i) {
            const int idx = i * 256 + tid;
            const int r   = idx >> 3;
            const int kq  = (idx & 7) * 4;
            const int g   = kq >> 3;
            const int k0  = kq & 7;
            *(uint2*)&Als[g * APLANE + r * AROW + k0] =
                *(const uint2*)(xb + (size_t)(row0 + r) * DIM + kt + kq);
            *(uint2*)&Bls[g * APLANE + r * AROW + k0] =
                *(const uint2*)(wb + (size_t)(col0 + r) * DIM + kt + kq);
        }
        __syncthreads();

        bf16x8 afr[4], bfr[4];
#pragma unroll
        for (int mi = 0; mi < 4; ++mi)
            afr[mi] = *(const bf16x8*)&Als[kg * APLANE + (wr * 64 + mi * 16 + fr) * AROW];
#pragma unroll
        for (int ni = 0; ni < 4; ++ni)
            bfr[ni] = *(const bf16x8*)&Bls[kg * APLANE + (wc * 64 + ni * 16 + fr) * AROW];
#pragma unroll
        for (int mi = 0; mi < 4; ++mi)
#pragma unroll
            for (int ni = 0; ni < 4; ++ni)
                acc[mi][ni] = __builtin_amdgcn_mfma_f32_16x16x32_bf16(
                    afr[mi], bfr[ni], acc[mi][ni], 0, 0, 0);
        __syncthreads();
    }

    // epilogue: candidate test + block-staged append (no Y write)
    const unsigned T = sl[SL_T32];
#pragma unroll
    for (int ni = 0; ni < 4; ++ni) {
        const int col = col0 + wc * 64 + ni * 16 + fr;
        const float be = benc[col];
#pragma unroll
        for (int mi = 0; mi < 4; ++mi) {
            const int rbase = row0 + wr * 64 + mi * 16 + kg * 4;
#pragma unroll
            for (int j = 0; j < 4; ++j) {
                unsigned short bits = bf16r(fmaxf(acc[mi][ni][j] + be, 0.f));
                if ((unsigned)bits >= T) {
                    unsigned p = atomicAdd(&lcnt, 1u);
                    if (p < (unsigned)LSTAGE) loc[p] = (rbase + j) * FEAT + col;
                }
            }
        }
    }
    __syncthreads();
    unsigned n = lcnt;
    if (n > (unsigned)LSTAGE) n = (unsigned)LSTAGE;
    if (tid == 0) gbase = atomicAdd(&sl[SL_NC], n);
    __syncthreads();
    const unsigned base = gbase;
    for (unsigned k = tid; k < n; k += 256) {
        unsigned dst = base + k;
        if (dst < (unsigned)CCAP) cand_raw[dst] = loc[k];
    }
}

// ===========================================================================
// W_dec transpose -> bf16
// ===========================================================================
__global__ void sae18_wt(const float* __restrict__ Wdec,
                         unsigned short* __restrict__ Wtb)
{
    __shared__ float t[32][33];
    const int f0 = blockIdx.x * 32;
    const int d0 = blockIdx.y * 32;
    const int tx = threadIdx.x;
    const int ty = threadIdx.y;
#pragma unroll
    for (int i = 0; i < 4; ++i)
        t[ty + i * 8][tx] = Wdec[(size_t)(d0 + ty + i * 8) * FEAT + f0 + tx];
    __syncthreads();
#pragma unroll
    for (int i = 0; i < 4; ++i)
        Wtb[(size_t)(f0 + ty + i * 8) * DIM + d0 + tx] = bf16r(t[tx][ty + i * 8]);
}

// ===========================================================================
// Feature-major candidate reorder (counting sort by feature id)
// ===========================================================================
__global__ __launch_bounds__(256) void sae18_fhist(const int* __restrict__ cand_raw,
                                                   const unsigned* __restrict__ sl,
                                                   unsigned* __restrict__ fhist)
{
    __shared__ unsigned h[16384];
    const int t = threadIdx.x;
    for (int i = t; i < 16384; i += 256) h[i] = 0u;
    __syncthreads();
    unsigned NC = sl[SL_NC];
    if (NC > (unsigned)CCAP) NC = (unsigned)CCAP;
    for (int i = blockIdx.x * 256 + t; i < (int)NC; i += gridDim.x * 256)
        atomicAdd(&h[cand_raw[i] & (FEAT - 1)], 1u);
    __syncthreads();
    for (int i = t; i < 16384; i += 256) {
        unsigned c = h[i];
        if (c) atomicAdd(&fhist[i], c);
    }
}

__global__ __launch_bounds__(1024) void sae18_fscan(const unsigned* __restrict__ fhist,
                                                    unsigned* __restrict__ fofs)
{
    __shared__ unsigned s[1024];
    const int t = threadIdx.x;
    unsigned c[16];
    unsigned sum = 0;
#pragma unroll
    for (int j = 0; j < 16; ++j) { c[j] = fhist[t * 16 + j]; sum += c[j]; }
    s[t] = sum;
    __syncthreads();
    for (int off = 1; off < 1024; off <<= 1) {
        unsigned v = (t >= off) ? s[t - off] : 0u;
        __syncthreads();
        s[t] += v;
        __syncthreads();
    }
    unsigned run = s[t] - sum;
#pragma unroll
    for (int j = 0; j < 16; ++j) { fofs[t * 16 + j] = run; run += c[j]; }
}

__global__ __launch_bounds__(256) void sae18_fscat(const int* __restrict__ cand_raw,
                                                   const unsigned* __restrict__ sl,
                                                   const unsigned* __restrict__ fofs,
                                                   unsigned* __restrict__ fcur,
                                                   int* __restrict__ cand_flat)
{
    unsigned NC = sl[SL_NC];
    if (NC > (unsigned)CCAP) NC = (unsigned)CCAP;
    for (int i = blockIdx.x * 256 + threadIdx.x; i < (int)NC; i += gridDim.x * 256) {
        int flat = cand_raw[i];
        int f = flat & (FEAT - 1);
        unsigned p = atomicAdd(&fcur[f], 1u);
        unsigned dst = fofs[f] + p;
        if (dst < (unsigned)CCAP) cand_flat[dst] = flat;
    }
}

// ===========================================================================
// f64 exact evaluation — FG candidates/wave, reg-cached Wenc row, XCD swizzle
// ===========================================================================
__global__ __launch_bounds__(256) void sae18_feval(const float* __restrict__ x,
                                                   const float* __restrict__ Wenc,
                                                   const float* __restrict__ benc,
                                                   const float* __restrict__ bdec,
                                                   const unsigned* __restrict__ sl,
                                                   const int* __restrict__ cand_flat,
                                                   u64* __restrict__ cand_key)
{
    unsigned NC = sl[SL_NC];
    if (NC > (unsigned)CCAP) NC = (unsigned)CCAP;
    const int lane = threadIdx.x & 63;
    const int b = blockIdx.x;
    const int lb = (b & 7) * (FBLK / 8) + (b >> 3);
    const int wid = lb * 4 + (threadIdx.x >> 6);
    const int c0 = wid * FG;
    if (c0 >= (int)NC) return;

    float bd[12], wv[12];
#pragma unroll
    for (int j = 0; j < 12; ++j) bd[j] = bdec[lane + j * 64];
    int fprev = -1;

    for (int g = 0; g < FG; ++g) {
        const int c = c0 + g;
        if (c >= (int)NC) break;
        const int flat = cand_flat[c];
        const int bb = flat >> 14;
        const int f  = flat & (FEAT - 1);
        if (f != fprev) {
            const float* wr = Wenc + (size_t)f * DIM;
#pragma unroll
            for (int j = 0; j < 12; ++j) wv[j] = wr[lane + j * 64];
            fprev = f;
        }
        const float* xr = x + (size_t)bb * DIM;
        double p = 0.0;
#pragma unroll
        for (int j = 0; j < 12; ++j)
            p = fma((double)xr[lane + j * 64] - (double)bd[j], (double)wv[j], p);
#pragma unroll
        for (int o = 32; o > 0; o >>= 1) p += __shfl_xor(p, o, 64);
        if (lane == 0) {
            p += (double)benc[f];
            if (p < 0.0) p = 0.0;
            cand_key[c] = (u64)__double_as_longlong(p);
        }
    }
}

// ===========================================================================
// u64 radix histogram — 3 LDS-privatized 14-bit passes (42-bit prefix)
// ===========================================================================
__global__ __launch_bounds__(256) void sae18_hist64(const u64* __restrict__ cand_key,
                                                    const unsigned* __restrict__ sl,
                                                    unsigned* __restrict__ hist,
                                                    int pass)
{
    __shared__ unsigned h[16384];
    const int t = threadIdx.x;
    for (int i = t; i < 16384; i += 256) h[i] = 0u;
    __syncthreads();

    unsigned NC = sl[SL_NC];
    if (NC > (unsigned)CCAP) NC = (unsigned)CCAP;
    u64 pref = 0;
    for (int i = 0; i < pass; ++i) pref = (pref << 14) | (u64)sl[SL_S0 + i];
    const int chk_sh = 64 - 14 * pass;
    const int bkt_sh = 50 - 14 * pass;

    for (int i = blockIdx.x * 256 + t; i < (int)NC; i += gridDim.x * 256) {
        u64 key = cand_key[i];
        if (pass > 0 && (key >> chk_sh) != pref) continue;
        atomicAdd(&h[(unsigned)(key >> bkt_sh) & 0x3FFFu], 1u);
    }
    __syncthreads();
    for (int i = t; i < 16384; i += 256) {
        unsigned c = h[i];
        if (c) atomicAdd(&hist[i], c);
    }
}

// ===========================================================================
// 14-bit k-th select per radix pass (rank-K)
// ===========================================================================
__global__ __launch_bounds__(1024) void sae18_sel14(const unsigned* __restrict__ hist,
                                                    unsigned* sl, int pass)
{
    __shared__ unsigned s[1024];
    const int t = threadIdx.x;
    const int C = 16;
    const unsigned N = (pass == 0) ? (unsigned)KB_SEL : sl[SL_S0 + 4 + pass - 1];
    const int lo = t * C;
    unsigned S = 0;
    for (int i = 0; i < C; ++i) S += hist[lo + i];
    s[t] = S;
    __syncthreads();
    for (int off = 1; off < 1024; off <<= 1) {
        unsigned v = (t + off < 1024) ? s[t + off] : 0u;
        __syncthreads();
        s[t] += v;
        __syncthreads();
    }
    const unsigned incl  = s[t];
    const unsigned above = incl - S;
    if (above < N && N <= incl) {
        unsigned cum = above;
        for (int i = lo + C - 1; i >= lo; --i) {
            cum += hist[i];
            if (cum >= N) {
                sl[SL_S0 + pass]     = (unsigned)i;
                sl[SL_S0 + 4 + pass] = N - (cum - hist[i]);
                break;
            }
        }
    }
}

// ===========================================================================
// Max key strictly below rank-K prefix group == rank-(K+1) key
// ===========================================================================
__global__ __launch_bounds__(256) void sae18_maxb(const u64* __restrict__ cand_key,
                                                  const unsigned* __restrict__ sl,
                                                  u64* __restrict__ mx)
{
    unsigned NC = sl[SL_NC];
    if (NC > (unsigned)CCAP) NC = (unsigned)CCAP;
    const u64 Tsh1 = ((u64)sl[SL_S0 + 0] << 28) | ((u64)sl[SL_S0 + 1] << 14) |
                     (u64)sl[SL_S0 + 2];
    u64 m = 0;
    for (int i = blockIdx.x * 256 + threadIdx.x; i < (int)NC; i += gridDim.x * 256) {
        u64 k = cand_key[i];
        if ((k >> 22) < Tsh1 && k > m) m = k;
    }
#pragma unroll
    for (int o = 32; o > 0; o >>= 1) {
        u64 o2 = __shfl_xor(m, o, 64);
        if (o2 > m) m = o2;
    }
    if ((threadIdx.x & 63) == 0 && m) atomicMax((unsigned long long*)mx, m);
}

// ===========================================================================
// Final classify with BOUNDARY SWAP (42-bit prefixes)
// ===========================================================================
__global__ __launch_bounds__(256) void sae18_class(const u64* __restrict__ cand_key,
                                                   const int* __restrict__ cand_flat,
                                                   const u64* __restrict__ mx,
                                                   unsigned* __restrict__ sl,
                                                   unsigned* __restrict__ row_cnt,
                                                   int* __restrict__ sel_flat,
                                                   float* __restrict__ sel_val,
                                                   int* __restrict__ tie_flat,
                                                   u64* __restrict__ tie_key)
{
    unsigned NC = sl[SL_NC];
    if (NC > (unsigned)CCAP) NC = (unsigned)CCAP;
    const u64 Tsh1 = ((u64)sl[SL_S0 + 0] << 28) | ((u64)sl[SL_S0 + 1] << 14) |
                     (u64)sl[SL_S0 + 2];
    const u64 Tsh2 = mx[0] >> 22;
    const int c = blockIdx.x * 256 + threadIdx.x;
    const bool active = (c < (int)NC);
    u64 key = 0;
    int flat = 0;
    u64 keysh = 0;
    if (active) {
        key = cand_key[c];
        keysh = key >> 22;
        flat = cand_flat[c];
    }
    const bool selp = active && (keysh > Tsh1);
    unsigned p = wave_append(&sl[SL_DEF], selp);
    if (selp && p < (unsigned)KB_SEL) {
        sel_flat[p] = flat;
        sel_val[p]  = (float)__longlong_as_double((long long)key);
        atomicAdd(&row_cnt[flat >> 14], 1u);
    }
    const bool tiep = active && !selp && (keysh == Tsh2);
    unsigned q = wave_append(&sl[SL_NTIE], tiep);
    if (tiep && q < (unsigned)TIE_CAP) { tie_flat[q] = flat; tie_key[q] = key; }
}

// ===========================================================================
// Tie/swap resolve: REM lowest flat indices
// ===========================================================================
__global__ __launch_bounds__(256) void sae18_ties(const int* __restrict__ tie_flat,
                                                  const u64* __restrict__ tie_key,
                                                  unsigned* __restrict__ sl,
                                                  int* __restrict__ sel_flat,
                                                  float* __restrict__ sel_val,
                                                  unsigned* __restrict__ row_cnt)
{
    unsigned R = sl[SL_NTIE];
    if (R > (unsigned)TIE_CAP) R = (unsigned)TIE_CAP;
    const unsigned REM = sl[SL_S0 + 6];
    const unsigned D = sl[SL_DEF];
    const int c = blockIdx.x * blockDim.x + threadIdx.x;
    if (c >= (int)R) return;
    const int ic = tie_flat[c];
    unsigned rank = 0;
    for (int j = 0; j < (int)R; ++j)
        if (tie_flat[j] < ic) ++rank;
    if (rank < REM) {
        unsigned p = D + atomicAdd(&sl[SL_WIN], 1u);
        if (p < (unsigned)KB_SEL) {
            sel_flat[p] = ic;
            sel_val[p]  = (float)__longlong_as_double((long long)tie_key[c]);
            atomicAdd(&row_cnt[ic >> 14], 1u);
        }
    }
}

// ===========================================================================
// Row prefix sum
// ===========================================================================
__global__ __launch_bounds__(256) void sae18_scan(const unsigned* __restrict__ row_cnt,
                                                  unsigned* __restrict__ row_ofs)
{
    __shared__ unsigned s[256];
    const int t = threadIdx.x;
    unsigned c[8];
    unsigned sum = 0;
#pragma unroll
    for (int j = 0; j < 8; ++j) { c[j] = row_cnt[t * 8 + j]; sum += c[j]; }
    s[t] = sum;
    __syncthreads();
    for (int off = 1; off < 256; off <<= 1) {
        unsigned v = (t >= off) ? s[t - off] : 0u;
        __syncthreads();
        s[t] += v;
        __syncthreads();
    }
    unsigned run = s[t] - sum;
#pragma unroll
    for (int j = 0; j < 8; ++j) { row_ofs[t * 8 + j] = run; run += c[j]; }
    if (t == 255) row_ofs[2048] = run;
}

// ===========================================================================
// Scatter into row-grouped arrays
// ===========================================================================
__global__ void sae18_scatter(const int* __restrict__ sel_flat,
                              const float* __restrict__ sel_val,
                              const unsigned* __restrict__ row_ofs,
                              unsigned* __restrict__ cursor,
                              int* __restrict__ gf, float* __restrict__ gv)
{
    int e = blockIdx.x * blockDim.x + threadIdx.x;
    if (e >= KB_SEL) return;
    int flat = sel_flat[e];
    int b = flat >> 14;
    unsigned p = atomicAdd(&cursor[b], 1u);
    unsigned dst = row_ofs[b] + p;
    if (dst < (unsigned)KB_SEL) {
        gf[dst] = flat & (FEAT - 1);
        gv[dst] = sel_val[e];
    }
}

// ===========================================================================
// Sparse decode — reads bf16 Wt
// ===========================================================================
__global__ __launch_bounds__(256) void sae18_decode(const int* __restrict__ gf,
                                                    const float* __restrict__ gv,
                                                    const unsigned* __restrict__ row_ofs,
                                                    const unsigned short* __restrict__ Wtb,
                                                    const float* __restrict__ bdec,
                                                    float* __restrict__ out)
{
    const int b = blockIdx.x;
    const int t = threadIdx.x;
    float a0 = 0.f, a1 = 0.f, a2 = 0.f;
    const unsigned s = row_ofs[b];
    const unsigned e = row_ofs[b + 1];
    for (unsigned i = s; i < e; ++i) {
        const int f   = gf[i];
        const float v = gv[i];
        const unsigned short* w = Wtb + (size_t)f * DIM;
        a0 = fmaf(v, __uint_as_float((unsigned)w[t]       << 16), a0);
        a1 = fmaf(v, __uint_as_float((unsigned)w[t + 256] << 16), a1);
        a2 = fmaf(v, __uint_as_float((unsigned)w[t + 512] << 16), a2);
    }
    out[(size_t)b * DIM + t]       = a0 + bdec[t];
    out[(size_t)b * DIM + t + 256] = a1 + bdec[t + 256];
    out[(size_t)b * DIM + t + 512] = a2 + bdec[t + 512];
}

// ===========================================================================
extern "C" void kernel_launch(void* const* d_in, const int* in_sizes, int n_in,
                              void* d_out, int out_size, void* d_ws, size_t ws_size,
                              hipStream_t stream)
{
    (void)in_sizes; (void)n_in; (void)out_size;
    const float* x    = (const float*)d_in[0];
    const float* Wenc = (const float*)d_in[1];
    const float* benc = (const float*)d_in[2];
    const float* Wdec = (const float*)d_in[3];
    const float* bdec = (const float*)d_in[4];
    float* out = (float*)d_out;

    char* ws = (char*)d_ws;
    size_t off = 0;
    unsigned short* Wtb = (unsigned short*)(ws + off);     off += (size_t)FEAT * DIM * 2;
    unsigned short* xb  = (unsigned short*)(ws + off);     off += (size_t)BATCH * DIM * 2;
    unsigned short* wb  = (unsigned short*)(ws + off);     off += (size_t)FEAT * DIM * 2;
    u64*      cand_key  = (u64*)(ws + off);                off += (size_t)CCAP * 8;
    int*      cand_raw  = (int*)(ws + off);                off += (size_t)CCAP * 4;
    int*      cand_flat = (int*)(ws + off);                off += (size_t)CCAP * 4;
    int*      tie_flat  = (int*)(ws + off);                off += (size_t)TIE_CAP * 4;
    u64*      tie_key   = (u64*)(ws + off);                off += (size_t)TIE_CAP * 8;
    unsigned* row_ofs   = (unsigned*)(ws + off);           off += 2052 * 4;
    unsigned* fofs      = (unsigned*)(ws + off);           off += 16384 * 4;
    // ---- contiguous ZERO ZONE (single memset) ----
    char* zstart = ws + off;
    int*      sel_flat  = (int*)(ws + off);                off += (size_t)KB_SEL * 4;
    float*    sel_val   = (float*)(ws + off);              off += (size_t)KB_SEL * 4;
    int*      gf        = (int*)(ws + off);                off += (size_t)KB_SEL * 4;
    float*    gv        = (float*)(ws + off);              off += (size_t)KB_SEL * 4;
    unsigned* hist1     = (unsigned*)(ws + off);           off += 8192 * 4;
    unsigned* h64       = (unsigned*)(ws + off);           off += 3 * 16384 * 4;
    unsigned* fhist     = (unsigned*)(ws + off);           off += 16384 * 4;
    unsigned* fcur      = (unsigned*)(ws + off);           off += 16384 * 4;
    unsigned* row_cnt   = (unsigned*)(ws + off);           off += 2048 * 4;
    unsigned* cursor    = (unsigned*)(ws + off);           off += 2048 * 4;
    u64*      mx        = (u64*)(ws + off);                off += 8;
    unsigned* sl        = (unsigned*)(ws + off);           off += 256;
    const size_t zbytes = (size_t)((ws + off) - zstart);
    if (ws_size < off) return;

    hipMemsetAsync(zstart, 0, zbytes, stream);

    // pre-convert + decoder transpose (bf16)
    sae18_prep<<<4096, 256, 0, stream>>>(x, Wenc, bdec, xb, wb);
    sae18_wt<<<dim3(FEAT / 32, DIM / 32), dim3(32, 8), 0, stream>>>(Wdec, Wtb);

    // sample GEMM (128 rows) -> histogram -> prune threshold
    sae18_sgemm<<<dim3(FEAT / GBN, 1), 256, 0, stream>>>(xb, wb, benc, hist1);
    sae18_selb<<<1, 1024, 0, stream>>>(hist1, sl);

    // main GEMM with inline candidate append (Y never materialized)
    sae18_gemm<<<dim3(FEAT / GBN, BATCH / GBM), 256, 0, stream>>>(xb, wb, benc, sl, cand_raw);

    // feature-major reorder -> exact f64 keys
    sae18_fhist<<<256, 256, 0, stream>>>(cand_raw, sl, fhist);
    sae18_fscan<<<1, 1024, 0, stream>>>(fhist, fofs);
    sae18_fscat<<<256, 256, 0, stream>>>(cand_raw, sl, fofs, fcur, cand_flat);
    sae18_feval<<<FBLK, 256, 0, stream>>>(x, Wenc, benc, bdec, sl, cand_flat, cand_key);

    // rank-K 42-bit prefix (3 passes) + rank-(K+1) via max-below
    for (int p = 0; p < 3; ++p) {
        sae18_hist64<<<256, 256, 0, stream>>>(cand_key, sl, h64 + p * 16384, p);
        sae18_sel14<<<1, 1024, 0, stream>>>(h64 + p * 16384, sl, p);
    }
    sae18_maxb<<<256, 256, 0, stream>>>(cand_key, sl, mx);

    // selection with rank-K <-> rank-(K+1) boundary swap
    sae18_class<<<(CCAP + 255) / 256, 256, 0, stream>>>(cand_key, cand_flat, mx, sl, row_cnt,
                                                        sel_flat, sel_val, tie_flat, tie_key);
    sae18_ties<<<TIE_CAP / 256, 256, 0, stream>>>(tie_flat, tie_key, sl,
                                                  sel_flat, sel_val, row_cnt);

    // group by batch row and decode sparsely (bf16 Wt)
    sae18_scan<<<1, 256, 0, stream>>>(row_cnt, row_ofs);
    sae18_scatter<<<(KB_SEL + 255) / 256, 256, 0, stream>>>(sel_flat, sel_val, row_ofs, cursor, gf, gv);
    sae18_decode<<<BATCH, 256, 0, stream>>>(gf, gv, row_ofs, Wtb, bdec, out);
}

// Round 23
// 432.049 us; speedup vs baseline: 1.1660x; 1.0061x over previous
//
#include <hip/hip_runtime.h>
#include <stdint.h>

// Problem constants
#define BATCH   2048
#define DIM     768
#define FEAT    16384
#define KSEL    64
#define KB_SEL  (BATCH * KSEL)      // 131072 selected
#define N_TOT   (BATCH * FEAT)      // 33554432
#define NX4     (BATCH * DIM / 4)
#define NW4     (FEAT * DIM / 4)

// MFMA GEMM tiling
#define GBM 128
#define GBN 128
#define GBK 32
#define AROW   24
#define APLANE 3088

// Threshold from 128-row sample GEMM; main GEMM appends candidates inline.
#define SAMP_ROWS 128
#define SAMP_N    12288
#define CCAP      262144
#define TIE_CAP   1024
#define LSTAGE    2048
#define FG        8
#define FBLK      (CCAP / (FG * 4))  // 8192 blocks, %8==0 -> bijective swizzle

// merged prep+wt grid split
#define PREP_BLKS 4096
#define WT_BLKS   (512 * 24)         // (FEAT/32) * (DIM/32)

// scalar slots
#define SL_T32    0
#define SL_NC     1
#define SL_DEF    2
#define SL_NTIE   3
#define SL_WIN    4
#define SL_S0     16

typedef __attribute__((ext_vector_type(8))) __bf16 bf16x8;
typedef __attribute__((ext_vector_type(4))) float  f32x4;
typedef unsigned long long u64;

__device__ __forceinline__ unsigned short bf16r(float v)
{
    unsigned u = __float_as_uint(v);
    u += 0x7FFFu + ((u >> 16) & 1u);
    return (unsigned short)(u >> 16);
}

__device__ __forceinline__ unsigned wave_append(unsigned* counter, bool pred)
{
    unsigned long long m = __ballot(pred);
    if (m == 0ull) return 0xFFFFFFFFu;
    const int lane = threadIdx.x & 63;
    const int leader = __ffsll((unsigned long long)m) - 1;
    unsigned base = 0;
    if (lane == leader) base = atomicAdd(counter, (unsigned)__popcll(m));
    base = __shfl(base, leader, 64);
    if (!pred) return 0xFFFFFFFFu;
    return base + (unsigned)__popcll(m & ((1ull << lane) - 1ull));
}

// ===========================================================================
// MERGED prep + wt (round-23): blocks [0,PREP_BLKS) convert x->xb, Wenc->wb;
// blocks [PREP_BLKS, ...) transpose Wdec -> bf16 Wtb. Both memory-bound at
// ~2TB/s individually (latency-limited) — one launch overlaps their traffic.
// ===========================================================================
__global__ __launch_bounds__(256) void sae19_prepwt(const float* __restrict__ x,
                                                    const float* __restrict__ Wenc,
                                                    const float* __restrict__ Wdec,
                                                    const float* __restrict__ bdec,
                                                    unsigned short* __restrict__ xb,
                                                    unsigned short* __restrict__ wb,
                                                    unsigned short* __restrict__ Wtb)
{
    __shared__ float t[32][33];
    if (blockIdx.x < PREP_BLKS) {
        const int tot = NX4 + NW4;
        for (int i = blockIdx.x * 256 + threadIdx.x; i < tot; i += PREP_BLKS * 256) {
            if (i < NX4) {
                const int e = i * 4;
                const int d = e % DIM;
                float4 v  = *(const float4*)(x + e);
                float4 dv = *(const float4*)(bdec + d);
                uint2 p;
                p.x = (unsigned)bf16r(v.x - dv.x) | ((unsigned)bf16r(v.y - dv.y) << 16);
                p.y = (unsigned)bf16r(v.z - dv.z) | ((unsigned)bf16r(v.w - dv.w) << 16);
                *(uint2*)(xb + e) = p;
            } else {
                const int e = (i - NX4) * 4;
                float4 v = *(const float4*)(Wenc + e);
                uint2 p;
                p.x = (unsigned)bf16r(v.x) | ((unsigned)bf16r(v.y) << 16);
                p.y = (unsigned)bf16r(v.z) | ((unsigned)bf16r(v.w) << 16);
                *(uint2*)(wb + e) = p;
            }
        }
    } else {
        const int wtb = blockIdx.x - PREP_BLKS;     // 0 .. WT_BLKS-1
        const int f0 = (wtb % 512) * 32;
        const int d0 = (wtb / 512) * 32;
        const int tx = threadIdx.x & 31;
        const int ty = threadIdx.x >> 5;            // 0..7
#pragma unroll
        for (int i = 0; i < 4; ++i)
            t[ty + i * 8][tx] = Wdec[(size_t)(d0 + ty + i * 8) * FEAT + f0 + tx];
        __syncthreads();
#pragma unroll
        for (int i = 0; i < 4; ++i)
            Wtb[(size_t)(f0 + ty + i * 8) * DIM + d0 + tx] = bf16r(t[tx][ty + i * 8]);
    }
}

// ===========================================================================
// SAMPLE GEMM (rows 0..127): epilogue histograms bf16 bits into LDS bins
// ===========================================================================
__global__ __launch_bounds__(256) void sae19_sgemm(const unsigned short* __restrict__ xb,
                                                   const unsigned short* __restrict__ wb,
                                                   const float* __restrict__ benc,
                                                   unsigned* __restrict__ hist)
{
    __shared__ unsigned short Als[4 * APLANE];
    __shared__ unsigned short Bls[4 * APLANE];
    __shared__ unsigned h[8192];

    const int tid  = threadIdx.x;
    for (int i = tid; i < 8192; i += 256) h[i] = 0u;
    const int row0 = 0;
    const int col0 = blockIdx.x * GBN;
    const int wid  = tid >> 6;
    const int lane = tid & 63;
    const int wr = wid >> 1;
    const int wc = wid & 1;
    const int fr = lane & 15;
    const int kg = lane >> 4;

    f32x4 acc[4][4];
#pragma unroll
    for (int i = 0; i < 4; ++i)
#pragma unroll
        for (int j = 0; j < 4; ++j) acc[i][j] = (f32x4){0.f, 0.f, 0.f, 0.f};

    for (int kt = 0; kt < DIM; kt += GBK) {
#pragma unroll
        for (int i = 0; i < 4; ++i) {
            const int idx = i * 256 + tid;
            const int r   = idx >> 3;
            const int kq  = (idx & 7) * 4;
            const int g   = kq >> 3;
            const int k0  = kq & 7;
            *(uint2*)&Als[g * APLANE + r * AROW + k0] =
                *(const uint2*)(xb + (size_t)(row0 + r) * DIM + kt + kq);
            *(uint2*)&Bls[g * APLANE + r * AROW + k0] =
                *(const uint2*)(wb + (size_t)(col0 + r) * DIM + kt + kq);
        }
        __syncthreads();

        bf16x8 afr[4], bfr[4];
#pragma unroll
        for (int mi = 0; mi < 4; ++mi)
            afr[mi] = *(const bf16x8*)&Als[kg * APLANE + (wr * 64 + mi * 16 + fr) * AROW];
#pragma unroll
        for (int ni = 0; ni < 4; ++ni)
            bfr[ni] = *(const bf16x8*)&Bls[kg * APLANE + (wc * 64 + ni * 16 + fr) * AROW];
#pragma unroll
        for (int mi = 0; mi < 4; ++mi)
#pragma unroll
            for (int ni = 0; ni < 4; ++ni)
                acc[mi][ni] = __builtin_amdgcn_mfma_f32_16x16x32_bf16(
                    afr[mi], bfr[ni], acc[mi][ni], 0, 0, 0);
        __syncthreads();
    }

#pragma unroll
    for (int ni = 0; ni < 4; ++ni) {
        const int col = col0 + wc * 64 + ni * 16 + fr;
        const float be = benc[col];
#pragma unroll
        for (int mi = 0; mi < 4; ++mi) {
#pragma unroll
            for (int j = 0; j < 4; ++j) {
                unsigned short bits = bf16r(fmaxf(acc[mi][ni][j] + be, 0.f));
                if (bits) atomicAdd(&h[bits >> 2], 1u);
            }
        }
    }
    __syncthreads();
    for (int i = tid; i < 8192; i += 256) {
        unsigned c = h[i];
        if (c) atomicAdd(&hist[i], c);
    }
}

// ===========================================================================
// Prune-threshold select from sample hist
// ===========================================================================
__global__ __launch_bounds__(1024) void sae19_selb(const unsigned* __restrict__ hist,
                                                   unsigned* sl)
{
    __shared__ unsigned s[1024];
    const int t = threadIdx.x;
    const int C = 8;
    const unsigned N = (unsigned)SAMP_N;
    const int lo = t * C;
    unsigned S = 0;
    for (int i = 0; i < C; ++i) S += hist[lo + i];
    s[t] = S;
    __syncthreads();
    for (int off = 1; off < 1024; off <<= 1) {
        unsigned v = (t + off < 1024) ? s[t + off] : 0u;
        __syncthreads();
        s[t] += v;
        __syncthreads();
    }
    const unsigned incl  = s[t];
    const unsigned above = incl - S;
    if (above < N && N <= incl) {
        unsigned cum = above;
        for (int i = lo + C - 1; i >= lo; --i) {
            cum += hist[i];
            if (cum >= N) { sl[SL_T32] = (unsigned)i << 2; break; }
        }
    }
}

// ===========================================================================
// MAIN GEMM — inline candidate append; loc[] ALIASES Als (round-23: after
// the K-loop's final barrier Als is dead; reuse cuts LDS 57856 -> ~49.7KB,
// restoring the occupancy lost in round 22).
// ===========================================================================
__global__ __launch_bounds__(256) void sae19_gemm(const unsigned short* __restrict__ xb,
                                                  const unsigned short* __restrict__ wb,
                                                  const float* __restrict__ benc,
                                                  unsigned* __restrict__ sl,
                                                  int* __restrict__ cand_raw)
{
    __shared__ unsigned short Als[4 * APLANE];
    __shared__ unsigned short Bls[4 * APLANE];
    __shared__ unsigned lcnt;
    __shared__ unsigned gbase;

    const int tid  = threadIdx.x;
    if (tid == 0) lcnt = 0;
    const int row0 = blockIdx.y * GBM;
    const int col0 = blockIdx.x * GBN;
    const int wid  = tid >> 6;
    const int lane = tid & 63;
    const int wr = wid >> 1;
    const int wc = wid & 1;
    const int fr = lane & 15;
    const int kg = lane >> 4;

    f32x4 acc[4][4];
#pragma unroll
    for (int i = 0; i < 4; ++i)
#pragma unroll
        for (int j = 0; j < 4; ++j) acc[i][j] = (f32x4){0.f, 0.f, 0.f, 0.f};

    for (int kt = 0; kt < DIM; kt += GBK) {
#pragma unroll
        for (int i = 0; i < 4; ++i) {
            const int idx = i * 256 + tid;
            const int r   = idx >> 3;
            const int kq  = (idx & 7) * 4;
            const int g   = kq >> 3;
            const int k0  = kq & 7;
            *(uint2*)&Als[g * APLANE + r * AROW + k0] =
                *(const uint2*)(xb + (size_t)(row0 + r) * DIM + kt + kq);
            *(uint2*)&Bls[g * APLANE + r * AROW + k0] =
                *(const uint2*)(wb + (size_t)(col0 + r) * DIM + kt + kq);
        }
        __syncthreads();

        bf16x8 afr[4], bfr[4];
#pragma unroll
        for (int mi = 0; mi < 4; ++mi)
            afr[mi] = *(const bf16x8*)&Als[kg * APLANE + (wr * 64 + mi * 16 + fr) * AROW];
#pragma unroll
        for (int ni = 0; ni < 4; ++ni)
            bfr[ni] = *(const bf16x8*)&Bls[kg * APLANE + (wc * 64 + ni * 16 + fr) * AROW];
#pragma unroll
        for (int mi = 0; mi < 4; ++mi)
#pragma unroll
            for (int ni = 0; ni < 4; ++ni)
                acc[mi][ni] = __builtin_amdgcn_mfma_f32_16x16x32_bf16(
                    afr[mi], bfr[ni], acc[mi][ni], 0, 0, 0);
        __syncthreads();    // final iteration: all Als/Bls reads complete
    }

    // ---- epilogue: loc aliases Als (dead after the barrier above) ----
    int* loc = (int*)Als;
    const unsigned T = sl[SL_T32];
#pragma unroll
    for (int ni = 0; ni < 4; ++ni) {
        const int col = col0 + wc * 64 + ni * 16 + fr;
        const float be = benc[col];
#pragma unroll
        for (int mi = 0; mi < 4; ++mi) {
            const int rbase = row0 + wr * 64 + mi * 16 + kg * 4;
#pragma unroll
            for (int j = 0; j < 4; ++j) {
                unsigned short bits = bf16r(fmaxf(acc[mi][ni][j] + be, 0.f));
                if ((unsigned)bits >= T) {
                    unsigned p = atomicAdd(&lcnt, 1u);
                    if (p < (unsigned)LSTAGE) loc[p] = (rbase + j) * FEAT + col;
                }
            }
        }
    }
    __syncthreads();
    unsigned n = lcnt;
    if (n > (unsigned)LSTAGE) n = (unsigned)LSTAGE;
    if (tid == 0) gbase = atomicAdd(&sl[SL_NC], n);
    __syncthreads();
    const unsigned base = gbase;
    for (unsigned k = tid; k < n; k += 256) {
        unsigned dst = base + k;
        if (dst < (unsigned)CCAP) cand_raw[dst] = loc[k];
    }
}

// ===========================================================================
// Feature-major candidate reorder (counting sort by feature id)
// ===========================================================================
__global__ __launch_bounds__(256) void sae19_fhist(const int* __restrict__ cand_raw,
                                                   const unsigned* __restrict__ sl,
                                                   unsigned* __restrict__ fhist)
{
    __shared__ unsigned h[16384];
    const int t = threadIdx.x;
    for (int i = t; i < 16384; i += 256) h[i] = 0u;
    __syncthreads();
    unsigned NC = sl[SL_NC];
    if (NC > (unsigned)CCAP) NC = (unsigned)CCAP;
    for (int i = blockIdx.x * 256 + t; i < (int)NC; i += gridDim.x * 256)
        atomicAdd(&h[cand_raw[i] & (FEAT - 1)], 1u);
    __syncthreads();
    for (int i = t; i < 16384; i += 256) {
        unsigned c = h[i];
        if (c) atomicAdd(&fhist[i], c);
    }
}

__global__ __launch_bounds__(1024) void sae19_fscan(const unsigned* __restrict__ fhist,
                                                    unsigned* __restrict__ fofs)
{
    __shared__ unsigned s[1024];
    const int t = threadIdx.x;
    unsigned c[16];
    unsigned sum = 0;
#pragma unroll
    for (int j = 0; j < 16; ++j) { c[j] = fhist[t * 16 + j]; sum += c[j]; }
    s[t] = sum;
    __syncthreads();
    for (int off = 1; off < 1024; off <<= 1) {
        unsigned v = (t >= off) ? s[t - off] : 0u;
        __syncthreads();
        s[t] += v;
        __syncthreads();
    }
    unsigned run = s[t] - sum;
#pragma unroll
    for (int j = 0; j < 16; ++j) { fofs[t * 16 + j] = run; run += c[j]; }
}

__global__ __launch_bounds__(256) void sae19_fscat(const int* __restrict__ cand_raw,
                                                   const unsigned* __restrict__ sl,
                                                   const unsigned* __restrict__ fofs,
                                                   unsigned* __restrict__ fcur,
                                                   int* __restrict__ cand_flat)
{
    unsigned NC = sl[SL_NC];
    if (NC > (unsigned)CCAP) NC = (unsigned)CCAP;
    for (int i = blockIdx.x * 256 + threadIdx.x; i < (int)NC; i += gridDim.x * 256) {
        int flat = cand_raw[i];
        int f = flat & (FEAT - 1);
        unsigned p = atomicAdd(&fcur[f], 1u);
        unsigned dst = fofs[f] + p;
        if (dst < (unsigned)CCAP) cand_flat[dst] = flat;
    }
}

// ===========================================================================
// f64 exact evaluation — FG candidates/wave, reg-cached Wenc row, XCD swizzle
// ===========================================================================
__global__ __launch_bounds__(256) void sae19_feval(const float* __restrict__ x,
                                                   const float* __restrict__ Wenc,
                                                   const float* __restrict__ benc,
                                                   const float* __restrict__ bdec,
                                                   const unsigned* __restrict__ sl,
                                                   const int* __restrict__ cand_flat,
                                                   u64* __restrict__ cand_key)
{
    unsigned NC = sl[SL_NC];
    if (NC > (unsigned)CCAP) NC = (unsigned)CCAP;
    const int lane = threadIdx.x & 63;
    const int b = blockIdx.x;
    const int lb = (b & 7) * (FBLK / 8) + (b >> 3);
    const int wid = lb * 4 + (threadIdx.x >> 6);
    const int c0 = wid * FG;
    if (c0 >= (int)NC) return;

    float bd[12], wv[12];
#pragma unroll
    for (int j = 0; j < 12; ++j) bd[j] = bdec[lane + j * 64];
    int fprev = -1;

    for (int g = 0; g < FG; ++g) {
        const int c = c0 + g;
        if (c >= (int)NC) break;
        const int flat = cand_flat[c];
        const int bb = flat >> 14;
        const int f  = flat & (FEAT - 1);
        if (f != fprev) {
            const float* wr = Wenc + (size_t)f * DIM;
#pragma unroll
            for (int j = 0; j < 12; ++j) wv[j] = wr[lane + j * 64];
            fprev = f;
        }
        const float* xr = x + (size_t)bb * DIM;
        double p = 0.0;
#pragma unroll
        for (int j = 0; j < 12; ++j)
            p = fma((double)xr[lane + j * 64] - (double)bd[j], (double)wv[j], p);
#pragma unroll
        for (int o = 32; o > 0; o >>= 1) p += __shfl_xor(p, o, 64);
        if (lane == 0) {
            p += (double)benc[f];
            if (p < 0.0) p = 0.0;
            cand_key[c] = (u64)__double_as_longlong(p);
        }
    }
}

// ===========================================================================
// u64 radix histogram — 3 LDS-privatized 14-bit passes (42-bit prefix)
// ===========================================================================
__global__ __launch_bounds__(256) void sae19_hist64(const u64* __restrict__ cand_key,
                                                    const unsigned* __restrict__ sl,
                                                    unsigned* __restrict__ hist,
                                                    int pass)
{
    __shared__ unsigned h[16384];
    const int t = threadIdx.x;
    for (int i = t; i < 16384; i += 256) h[i] = 0u;
    __syncthreads();

    unsigned NC = sl[SL_NC];
    if (NC > (unsigned)CCAP) NC = (unsigned)CCAP;
    u64 pref = 0;
    for (int i = 0; i < pass; ++i) pref = (pref << 14) | (u64)sl[SL_S0 + i];
    const int chk_sh = 64 - 14 * pass;
    const int bkt_sh = 50 - 14 * pass;

    for (int i = blockIdx.x * 256 + t; i < (int)NC; i += gridDim.x * 256) {
        u64 key = cand_key[i];
        if (pass > 0 && (key >> chk_sh) != pref) continue;
        atomicAdd(&h[(unsigned)(key >> bkt_sh) & 0x3FFFu], 1u);
    }
    __syncthreads();
    for (int i = t; i < 16384; i += 256) {
        unsigned c = h[i];
        if (c) atomicAdd(&hist[i], c);
    }
}

// ===========================================================================
// 14-bit k-th select per radix pass (rank-K)
// ===========================================================================
__global__ __launch_bounds__(1024) void sae19_sel14(const unsigned* __restrict__ hist,
                                                    unsigned* sl, int pass)
{
    __shared__ unsigned s[1024];
    const int t = threadIdx.x;
    const int C = 16;
    const unsigned N = (pass == 0) ? (unsigned)KB_SEL : sl[SL_S0 + 4 + pass - 1];
    const int lo = t * C;
    unsigned S = 0;
    for (int i = 0; i < C; ++i) S += hist[lo + i];
    s[t] = S;
    __syncthreads();
    for (int off = 1; off < 1024; off <<= 1) {
        unsigned v = (t + off < 1024) ? s[t + off] : 0u;
        __syncthreads();
        s[t] += v;
        __syncthreads();
    }
    const unsigned incl  = s[t];
    const unsigned above = incl - S;
    if (above < N && N <= incl) {
        unsigned cum = above;
        for (int i = lo + C - 1; i >= lo; --i) {
            cum += hist[i];
            if (cum >= N) {
                sl[SL_S0 + pass]     = (unsigned)i;
                sl[SL_S0 + 4 + pass] = N - (cum - hist[i]);
                break;
            }
        }
    }
}

// ===========================================================================
// Max key strictly below rank-K prefix group == rank-(K+1) key
// ===========================================================================
__global__ __launch_bounds__(256) void sae19_maxb(const u64* __restrict__ cand_key,
                                                  const unsigned* __restrict__ sl,
                                                  u64* __restrict__ mx)
{
    unsigned NC = sl[SL_NC];
    if (NC > (unsigned)CCAP) NC = (unsigned)CCAP;
    const u64 Tsh1 = ((u64)sl[SL_S0 + 0] << 28) | ((u64)sl[SL_S0 + 1] << 14) |
                     (u64)sl[SL_S0 + 2];
    u64 m = 0;
    for (int i = blockIdx.x * 256 + threadIdx.x; i < (int)NC; i += gridDim.x * 256) {
        u64 k = cand_key[i];
        if ((k >> 22) < Tsh1 && k > m) m = k;
    }
#pragma unroll
    for (int o = 32; o > 0; o >>= 1) {
        u64 o2 = __shfl_xor(m, o, 64);
        if (o2 > m) m = o2;
    }
    if ((threadIdx.x & 63) == 0 && m) atomicMax((unsigned long long*)mx, m);
}

// ===========================================================================
// Final classify with BOUNDARY SWAP (42-bit prefixes)
// ===========================================================================
__global__ __launch_bounds__(256) void sae19_class(const u64* __restrict__ cand_key,
                                                   const int* __restrict__ cand_flat,
                                                   const u64* __restrict__ mx,
                                                   unsigned* __restrict__ sl,
                                                   unsigned* __restrict__ row_cnt,
                                                   int* __restrict__ sel_flat,
                                                   float* __restrict__ sel_val,
                                                   int* __restrict__ tie_flat,
                                                   u64* __restrict__ tie_key)
{
    unsigned NC = sl[SL_NC];
    if (NC > (unsigned)CCAP) NC = (unsigned)CCAP;
    const u64 Tsh1 = ((u64)sl[SL_S0 + 0] << 28) | ((u64)sl[SL_S0 + 1] << 14) |
                     (u64)sl[SL_S0 + 2];
    const u64 Tsh2 = mx[0] >> 22;
    const int c = blockIdx.x * 256 + threadIdx.x;
    const bool active = (c < (int)NC);
    u64 key = 0;
    int flat = 0;
    u64 keysh = 0;
    if (active) {
        key = cand_key[c];
        keysh = key >> 22;
        flat = cand_flat[c];
    }
    const bool selp = active && (keysh > Tsh1);
    unsigned p = wave_append(&sl[SL_DEF], selp);
    if (selp && p < (unsigned)KB_SEL) {
        sel_flat[p] = flat;
        sel_val[p]  = (float)__longlong_as_double((long long)key);
        atomicAdd(&row_cnt[flat >> 14], 1u);
    }
    const bool tiep = active && !selp && (keysh == Tsh2);
    unsigned q = wave_append(&sl[SL_NTIE], tiep);
    if (tiep && q < (unsigned)TIE_CAP) { tie_flat[q] = flat; tie_key[q] = key; }
}

// ===========================================================================
// Tie/swap resolve: REM lowest flat indices
// ===========================================================================
__global__ __launch_bounds__(256) void sae19_ties(const int* __restrict__ tie_flat,
                                                  const u64* __restrict__ tie_key,
                                                  unsigned* __restrict__ sl,
                                                  int* __restrict__ sel_flat,
                                                  float* __restrict__ sel_val,
                                                  unsigned* __restrict__ row_cnt)
{
    unsigned R = sl[SL_NTIE];
    if (R > (unsigned)TIE_CAP) R = (unsigned)TIE_CAP;
    const unsigned REM = sl[SL_S0 + 6];
    const unsigned D = sl[SL_DEF];
    const int c = blockIdx.x * blockDim.x + threadIdx.x;
    if (c >= (int)R) return;
    const int ic = tie_flat[c];
    unsigned rank = 0;
    for (int j = 0; j < (int)R; ++j)
        if (tie_flat[j] < ic) ++rank;
    if (rank < REM) {
        unsigned p = D + atomicAdd(&sl[SL_WIN], 1u);
        if (p < (unsigned)KB_SEL) {
            sel_flat[p] = ic;
            sel_val[p]  = (float)__longlong_as_double((long long)tie_key[c]);
            atomicAdd(&row_cnt[ic >> 14], 1u);
        }
    }
}

// ===========================================================================
// Row prefix sum
// ===========================================================================
__global__ __launch_bounds__(256) void sae19_scan(const unsigned* __restrict__ row_cnt,
                                                  unsigned* __restrict__ row_ofs)
{
    __shared__ unsigned s[256];
    const int t = threadIdx.x;
    unsigned c[8];
    unsigned sum = 0;
#pragma unroll
    for (int j = 0; j < 8; ++j) { c[j] = row_cnt[t * 8 + j]; sum += c[j]; }
    s[t] = sum;
    __syncthreads();
    for (int off = 1; off < 256; off <<= 1) {
        unsigned v = (t >= off) ? s[t - off] : 0u;
        __syncthreads();
        s[t] += v;
        __syncthreads();
    }
    unsigned run = s[t] - sum;
#pragma unroll
    for (int j = 0; j < 8; ++j) { row_ofs[t * 8 + j] = run; run += c[j]; }
    if (t == 255) row_ofs[2048] = run;
}

// ===========================================================================
// Scatter into row-grouped arrays
// ===========================================================================
__global__ void sae19_scatter(const int* __restrict__ sel_flat,
                              const float* __restrict__ sel_val,
                              const unsigned* __restrict__ row_ofs,
                              unsigned* __restrict__ cursor,
                              int* __restrict__ gf, float* __restrict__ gv)
{
    int e = blockIdx.x * blockDim.x + threadIdx.x;
    if (e >= KB_SEL) return;
    int flat = sel_flat[e];
    int b = flat >> 14;
    unsigned p = atomicAdd(&cursor[b], 1u);
    unsigned dst = row_ofs[b] + p;
    if (dst < (unsigned)KB_SEL) {
        gf[dst] = flat & (FEAT - 1);
        gv[dst] = sel_val[e];
    }
}

// ===========================================================================
// Sparse decode — reads bf16 Wt
// ===========================================================================
__global__ __launch_bounds__(256) void sae19_decode(const int* __restrict__ gf,
                                                    const float* __restrict__ gv,
                                                    const unsigned* __restrict__ row_ofs,
                                                    const unsigned short* __restrict__ Wtb,
                                                    const float* __restrict__ bdec,
                                                    float* __restrict__ out)
{
    const int b = blockIdx.x;
    const int t = threadIdx.x;
    float a0 = 0.f, a1 = 0.f, a2 = 0.f;
    const unsigned s = row_ofs[b];
    const unsigned e = row_ofs[b + 1];
    for (unsigned i = s; i < e; ++i) {
        const int f   = gf[i];
        const float v = gv[i];
        const unsigned short* w = Wtb + (size_t)f * DIM;
        a0 = fmaf(v, __uint_as_float((unsigned)w[t]       << 16), a0);
        a1 = fmaf(v, __uint_as_float((unsigned)w[t + 256] << 16), a1);
        a2 = fmaf(v, __uint_as_float((unsigned)w[t + 512] << 16), a2);
    }
    out[(size_t)b * DIM + t]       = a0 + bdec[t];
    out[(size_t)b * DIM + t + 256] = a1 + bdec[t + 256];
    out[(size_t)b * DIM + t + 512] = a2 + bdec[t + 512];
}

// ===========================================================================
extern "C" void kernel_launch(void* const* d_in, const int* in_sizes, int n_in,
                              void* d_out, int out_size, void* d_ws, size_t ws_size,
                              hipStream_t stream)
{
    (void)in_sizes; (void)n_in; (void)out_size;
    const float* x    = (const float*)d_in[0];
    const float* Wenc = (const float*)d_in[1];
    const float* benc = (const float*)d_in[2];
    const float* Wdec = (const float*)d_in[3];
    const float* bdec = (const float*)d_in[4];
    float* out = (float*)d_out;

    char* ws = (char*)d_ws;
    size_t off = 0;
    unsigned short* Wtb = (unsigned short*)(ws + off);     off += (size_t)FEAT * DIM * 2;
    unsigned short* xb  = (unsigned short*)(ws + off);     off += (size_t)BATCH * DIM * 2;
    unsigned short* wb  = (unsigned short*)(ws + off);     off += (size_t)FEAT * DIM * 2;
    u64*      cand_key  = (u64*)(ws + off);                off += (size_t)CCAP * 8;
    int*      cand_raw  = (int*)(ws + off);                off += (size_t)CCAP * 4;
    int*      cand_flat = (int*)(ws + off);                off += (size_t)CCAP * 4;
    int*      tie_flat  = (int*)(ws + off);                off += (size_t)TIE_CAP * 4;
    u64*      tie_key   = (u64*)(ws + off);                off += (size_t)TIE_CAP * 8;
    unsigned* row_ofs   = (unsigned*)(ws + off);           off += 2052 * 4;
    unsigned* fofs      = (unsigned*)(ws + off);           off += 16384 * 4;
    // ---- contiguous ZERO ZONE (single memset) ----
    char* zstart = ws + off;
    int*      sel_flat  = (int*)(ws + off);                off += (size_t)KB_SEL * 4;
    float*    sel_val   = (float*)(ws + off);              off += (size_t)KB_SEL * 4;
    int*      gf        = (int*)(ws + off);                off += (size_t)KB_SEL * 4;
    float*    gv        = (float*)(ws + off);              off += (size_t)KB_SEL * 4;
    unsigned* hist1     = (unsigned*)(ws + off);           off += 8192 * 4;
    unsigned* h64       = (unsigned*)(ws + off);           off += 3 * 16384 * 4;
    unsigned* fhist     = (unsigned*)(ws + off);           off += 16384 * 4;
    unsigned* fcur      = (unsigned*)(ws + off);           off += 16384 * 4;
    unsigned* row_cnt   = (unsigned*)(ws + off);           off += 2048 * 4;
    unsigned* cursor    = (unsigned*)(ws + off);           off += 2048 * 4;
    u64*      mx        = (u64*)(ws + off);                off += 8;
    unsigned* sl        = (unsigned*)(ws + off);           off += 256;
    const size_t zbytes = (size_t)((ws + off) - zstart);
    if (ws_size < off) return;

    hipMemsetAsync(zstart, 0, zbytes, stream);

    // merged pre-convert + decoder transpose (one launch, overlapped traffic)
    sae19_prepwt<<<PREP_BLKS + WT_BLKS, 256, 0, stream>>>(x, Wenc, Wdec, bdec, xb, wb, Wtb);

    // sample GEMM (128 rows) -> histogram -> prune threshold
    sae19_sgemm<<<dim3(FEAT / GBN, 1), 256, 0, stream>>>(xb, wb, benc, hist1);
    sae19_selb<<<1, 1024, 0, stream>>>(hist1, sl);

    // main GEMM with inline candidate append (Y never materialized)
    sae19_gemm<<<dim3(FEAT / GBN, BATCH / GBM), 256, 0, stream>>>(xb, wb, benc, sl, cand_raw);

    // feature-major reorder -> exact f64 keys
    sae19_fhist<<<256, 256, 0, stream>>>(cand_raw, sl, fhist);
    sae19_fscan<<<1, 1024, 0, stream>>>(fhist, fofs);
    sae19_fscat<<<256, 256, 0, stream>>>(cand_raw, sl, fofs, fcur, cand_flat);
    sae19_feval<<<FBLK, 256, 0, stream>>>(x, Wenc, benc, bdec, sl, cand_flat, cand_key);

    // rank-K 42-bit prefix (3 passes) + rank-(K+1) via max-below
    for (int p = 0; p < 3; ++p) {
        sae19_hist64<<<256, 256, 0, stream>>>(cand_key, sl, h64 + p * 16384, p);
        sae19_sel14<<<1, 1024, 0, stream>>>(h64 + p * 16384, sl, p);
    }
    sae19_maxb<<<256, 256, 0, stream>>>(cand_key, sl, mx);

    // selection with rank-K <-> rank-(K+1) boundary swap
    sae19_class<<<(CCAP + 255) / 256, 256, 0, stream>>>(cand_key, cand_flat, mx, sl, row_cnt,
                                                        sel_flat, sel_val, tie_flat, tie_key);
    sae19_ties<<<TIE_CAP / 256, 256, 0, stream>>>(tie_flat, tie_key, sl,
                                                  sel_flat, sel_val, row_cnt);

    // group by batch row and decode sparsely (bf16 Wt)
    sae19_scan<<<1, 256, 0, stream>>>(row_cnt, row_ofs);
    sae19_scatter<<<(KB_SEL + 255) / 256, 256, 0, stream>>>(sel_flat, sel_val, row_ofs, cursor, gf, gv);
    sae19_decode<<<BATCH, 256, 0, stream>>>(gf, gv, row_ofs, Wtb, bdec, out);
}

// Round 24
// 426.277 us; speedup vs baseline: 1.1817x; 1.0135x over previous
//
#include <hip/hip_runtime.h>
#include <stdint.h>

// Problem constants
#define BATCH   2048
#define DIM     768
#define FEAT    16384
#define KSEL    64
#define KB_SEL  (BATCH * KSEL)      // 131072 selected
#define N_TOT   (BATCH * FEAT)      // 33554432
#define NX4     (BATCH * DIM / 4)
#define NW4     (FEAT * DIM / 4)

// MFMA GEMM tiling
#define GBM 128
#define GBN 128
#define GBK 32
#define AROW   24
#define APLANE 3088

// Threshold from 128-row sample GEMM; main GEMM appends candidates inline.
// SAMP_N 10752 -> full-rank target ~172K; min NC ~159K > 145K floor (8 sigma).
// f32-domain epilogue compare uses the bucket BELOW T (superset, <= +8K).
#define SAMP_ROWS 128
#define SAMP_N    10752
#define CCAP      262144
#define TIE_CAP   1024
#define LSTAGE    2048
#define FG        8
#define FBLK      (CCAP / (FG * 4))  // 8192 blocks, %8==0 -> bijective swizzle

// merged prep+wt grid split
#define PREP_BLKS 4096
#define WT_BLKS   (512 * 24)         // (FEAT/32) * (DIM/32)

// scalar slots
#define SL_T32    0
#define SL_NC     1
#define SL_DEF    2
#define SL_NTIE   3
#define SL_WIN    4
#define SL_THRF   8                  // f32 bits of bucket-below-T value
#define SL_S0     16

typedef __attribute__((ext_vector_type(8))) __bf16 bf16x8;
typedef __attribute__((ext_vector_type(4))) float  f32x4;
typedef unsigned long long u64;

__device__ __forceinline__ unsigned short bf16r(float v)
{
    unsigned u = __float_as_uint(v);
    u += 0x7FFFu + ((u >> 16) & 1u);
    return (unsigned short)(u >> 16);
}

__device__ __forceinline__ unsigned wave_append(unsigned* counter, bool pred)
{
    unsigned long long m = __ballot(pred);
    if (m == 0ull) return 0xFFFFFFFFu;
    const int lane = threadIdx.x & 63;
    const int leader = __ffsll((unsigned long long)m) - 1;
    unsigned base = 0;
    if (lane == leader) base = atomicAdd(counter, (unsigned)__popcll(m));
    base = __shfl(base, leader, 64);
    if (!pred) return 0xFFFFFFFFu;
    return base + (unsigned)__popcll(m & ((1ull << lane) - 1ull));
}

// ===========================================================================
// MERGED prep + wt
// ===========================================================================
__global__ __launch_bounds__(256) void sae20_prepwt(const float* __restrict__ x,
                                                    const float* __restrict__ Wenc,
                                                    const float* __restrict__ Wdec,
                                                    const float* __restrict__ bdec,
                                                    unsigned short* __restrict__ xb,
                                                    unsigned short* __restrict__ wb,
                                                    unsigned short* __restrict__ Wtb)
{
    __shared__ float t[32][33];
    if (blockIdx.x < PREP_BLKS) {
        const int tot = NX4 + NW4;
        for (int i = blockIdx.x * 256 + threadIdx.x; i < tot; i += PREP_BLKS * 256) {
            if (i < NX4) {
                const int e = i * 4;
                const int d = e % DIM;
                float4 v  = *(const float4*)(x + e);
                float4 dv = *(const float4*)(bdec + d);
                uint2 p;
                p.x = (unsigned)bf16r(v.x - dv.x) | ((unsigned)bf16r(v.y - dv.y) << 16);
                p.y = (unsigned)bf16r(v.z - dv.z) | ((unsigned)bf16r(v.w - dv.w) << 16);
                *(uint2*)(xb + e) = p;
            } else {
                const int e = (i - NX4) * 4;
                float4 v = *(const float4*)(Wenc + e);
                uint2 p;
                p.x = (unsigned)bf16r(v.x) | ((unsigned)bf16r(v.y) << 16);
                p.y = (unsigned)bf16r(v.z) | ((unsigned)bf16r(v.w) << 16);
                *(uint2*)(wb + e) = p;
            }
        }
    } else {
        const int wtb = blockIdx.x - PREP_BLKS;
        const int f0 = (wtb % 512) * 32;
        const int d0 = (wtb / 512) * 32;
        const int tx = threadIdx.x & 31;
        const int ty = threadIdx.x >> 5;
#pragma unroll
        for (int i = 0; i < 4; ++i)
            t[ty + i * 8][tx] = Wdec[(size_t)(d0 + ty + i * 8) * FEAT + f0 + tx];
        __syncthreads();
#pragma unroll
        for (int i = 0; i < 4; ++i)
            Wtb[(size_t)(f0 + ty + i * 8) * DIM + d0 + tx] = bf16r(t[tx][ty + i * 8]);
    }
}

// ===========================================================================
// SAMPLE GEMM (rows 0..127): epilogue histograms bf16 bits into LDS bins
// ===========================================================================
__global__ __launch_bounds__(256) void sae20_sgemm(const unsigned short* __restrict__ xb,
                                                   const unsigned short* __restrict__ wb,
                                                   const float* __restrict__ benc,
                                                   unsigned* __restrict__ hist)
{
    __shared__ unsigned short Als[4 * APLANE];
    __shared__ unsigned short Bls[4 * APLANE];
    __shared__ unsigned h[8192];

    const int tid  = threadIdx.x;
    for (int i = tid; i < 8192; i += 256) h[i] = 0u;
    const int row0 = 0;
    const int col0 = blockIdx.x * GBN;
    const int wid  = tid >> 6;
    const int lane = tid & 63;
    const int wr = wid >> 1;
    const int wc = wid & 1;
    const int fr = lane & 15;
    const int kg = lane >> 4;

    f32x4 acc[4][4];
#pragma unroll
    for (int i = 0; i < 4; ++i)
#pragma unroll
        for (int j = 0; j < 4; ++j) acc[i][j] = (f32x4){0.f, 0.f, 0.f, 0.f};

    for (int kt = 0; kt < DIM; kt += GBK) {
#pragma unroll
        for (int i = 0; i < 4; ++i) {
            const int idx = i * 256 + tid;
            const int r   = idx >> 3;
            const int kq  = (idx & 7) * 4;
            const int g   = kq >> 3;
            const int k0  = kq & 7;
            *(uint2*)&Als[g * APLANE + r * AROW + k0] =
                *(const uint2*)(xb + (size_t)(row0 + r) * DIM + kt + kq);
            *(uint2*)&Bls[g * APLANE + r * AROW + k0] =
                *(const uint2*)(wb + (size_t)(col0 + r) * DIM + kt + kq);
        }
        __syncthreads();

        bf16x8 afr[4], bfr[4];
#pragma unroll
        for (int mi = 0; mi < 4; ++mi)
            afr[mi] = *(const bf16x8*)&Als[kg * APLANE + (wr * 64 + mi * 16 + fr) * AROW];
#pragma unroll
        for (int ni = 0; ni < 4; ++ni)
            bfr[ni] = *(const bf16x8*)&Bls[kg * APLANE + (wc * 64 + ni * 16 + fr) * AROW];
#pragma unroll
        for (int mi = 0; mi < 4; ++mi)
#pragma unroll
            for (int ni = 0; ni < 4; ++ni)
                acc[mi][ni] = __builtin_amdgcn_mfma_f32_16x16x32_bf16(
                    afr[mi], bfr[ni], acc[mi][ni], 0, 0, 0);
        __syncthreads();
    }

#pragma unroll
    for (int ni = 0; ni < 4; ++ni) {
        const int col = col0 + wc * 64 + ni * 16 + fr;
        const float be = benc[col];
#pragma unroll
        for (int mi = 0; mi < 4; ++mi) {
#pragma unroll
            for (int j = 0; j < 4; ++j) {
                unsigned short bits = bf16r(fmaxf(acc[mi][ni][j] + be, 0.f));
                if (bits) atomicAdd(&h[bits >> 2], 1u);
            }
        }
    }
    __syncthreads();
    for (int i = tid; i < 8192; i += 256) {
        unsigned c = h[i];
        if (c) atomicAdd(&hist[i], c);
    }
}

// ===========================================================================
// Prune-threshold select from sample hist.
// Also writes SL_THRF = f32 bits of the bucket-BELOW-T lower bound, so the
// main GEMM can test candidates in f32 (no bf16r in its epilogue).
// pred (v > thrf) is a strict superset of (bf16r(v) >= T).
// ===========================================================================
__global__ __launch_bounds__(1024) void sae20_selb(const unsigned* __restrict__ hist,
                                                   unsigned* sl)
{
    __shared__ unsigned s[1024];
    const int t = threadIdx.x;
    const int C = 8;
    const unsigned N = (unsigned)SAMP_N;
    const int lo = t * C;
    unsigned S = 0;
    for (int i = 0; i < C; ++i) S += hist[lo + i];
    s[t] = S;
    __syncthreads();
    for (int off = 1; off < 1024; off <<= 1) {
        unsigned v = (t + off < 1024) ? s[t + off] : 0u;
        __syncthreads();
        s[t] += v;
        __syncthreads();
    }
    const unsigned incl  = s[t];
    const unsigned above = incl - S;
    if (above < N && N <= incl) {
        unsigned cum = above;
        for (int i = lo + C - 1; i >= lo; --i) {
            cum += hist[i];
            if (cum >= N) {
                sl[SL_T32] = (unsigned)i << 2;
                unsigned tb = (i > 0) ? ((unsigned)(i - 1) << 2) : 0u;
                sl[SL_THRF] = tb << 16;      // f32 bit pattern of bf16 value
                break;
            }
        }
    }
}

// ===========================================================================
// MAIN GEMM — inline candidate append, f32-domain compare (round-24:
// removes 64x bf16r+fmax per thread from the epilogue); loc aliases Als.
// ===========================================================================
__global__ __launch_bounds__(256) void sae20_gemm(const unsigned short* __restrict__ xb,
                                                  const unsigned short* __restrict__ wb,
                                                  const float* __restrict__ benc,
                                                  unsigned* __restrict__ sl,
                                                  int* __restrict__ cand_raw)
{
    __shared__ unsigned short Als[4 * APLANE];
    __shared__ unsigned short Bls[4 * APLANE];
    __shared__ unsigned lcnt;
    __shared__ unsigned gbase;

    const int tid  = threadIdx.x;
    if (tid == 0) lcnt = 0;
    const int row0 = blockIdx.y * GBM;
    const int col0 = blockIdx.x * GBN;
    const int wid  = tid >> 6;
    const int lane = tid & 63;
    const int wr = wid >> 1;
    const int wc = wid & 1;
    const int fr = lane & 15;
    const int kg = lane >> 4;

    f32x4 acc[4][4];
#pragma unroll
    for (int i = 0; i < 4; ++i)
#pragma unroll
        for (int j = 0; j < 4; ++j) acc[i][j] = (f32x4){0.f, 0.f, 0.f, 0.f};

    for (int kt = 0; kt < DIM; kt += GBK) {
#pragma unroll
        for (int i = 0; i < 4; ++i) {
            const int idx = i * 256 + tid;
            const int r   = idx >> 3;
            const int kq  = (idx & 7) * 4;
            const int g   = kq >> 3;
            const int k0  = kq & 7;
            *(uint2*)&Als[g * APLANE + r * AROW + k0] =
                *(const uint2*)(xb + (size_t)(row0 + r) * DIM + kt + kq);
            *(uint2*)&Bls[g * APLANE + r * AROW + k0] =
                *(const uint2*)(wb + (size_t)(col0 + r) * DIM + kt + kq);
        }
        __syncthreads();

        bf16x8 afr[4], bfr[4];
#pragma unroll
        for (int mi = 0; mi < 4; ++mi)
            afr[mi] = *(const bf16x8*)&Als[kg * APLANE + (wr * 64 + mi * 16 + fr) * AROW];
#pragma unroll
        for (int ni = 0; ni < 4; ++ni)
            bfr[ni] = *(const bf16x8*)&Bls[kg * APLANE + (wc * 64 + ni * 16 + fr) * AROW];
#pragma unroll
        for (int mi = 0; mi < 4; ++mi)
#pragma unroll
            for (int ni = 0; ni < 4; ++ni)
                acc[mi][ni] = __builtin_amdgcn_mfma_f32_16x16x32_bf16(
                    afr[mi], bfr[ni], acc[mi][ni], 0, 0, 0);
        __syncthreads();    // final iteration: all Als/Bls reads complete
    }

    // ---- epilogue: loc aliases Als; f32 compare against bucket-below-T ----
    int* loc = (int*)Als;
    const float thr = __uint_as_float(sl[SL_THRF]);
#pragma unroll
    for (int ni = 0; ni < 4; ++ni) {
        const int col = col0 + wc * 64 + ni * 16 + fr;
        const float be = benc[col];
#pragma unroll
        for (int mi = 0; mi < 4; ++mi) {
            const int rbase = row0 + wr * 64 + mi * 16 + kg * 4;
#pragma unroll
            for (int j = 0; j < 4; ++j) {
                if (acc[mi][ni][j] + be > thr) {
                    unsigned p = atomicAdd(&lcnt, 1u);
                    if (p < (unsigned)LSTAGE) loc[p] = (rbase + j) * FEAT + col;
                }
            }
        }
    }
    __syncthreads();
    unsigned n = lcnt;
    if (n > (unsigned)LSTAGE) n = (unsigned)LSTAGE;
    if (tid == 0) gbase = atomicAdd(&sl[SL_NC], n);
    __syncthreads();
    const unsigned base = gbase;
    for (unsigned k = tid; k < n; k += 256) {
        unsigned dst = base + k;
        if (dst < (unsigned)CCAP) cand_raw[dst] = loc[k];
    }
}

// ===========================================================================
// Feature-major candidate reorder (counting sort by feature id)
// ===========================================================================
__global__ __launch_bounds__(256) void sae20_fhist(const int* __restrict__ cand_raw,
                                                   const unsigned* __restrict__ sl,
                                                   unsigned* __restrict__ fhist)
{
    __shared__ unsigned h[16384];
    const int t = threadIdx.x;
    for (int i = t; i < 16384; i += 256) h[i] = 0u;
    __syncthreads();
    unsigned NC = sl[SL_NC];
    if (NC > (unsigned)CCAP) NC = (unsigned)CCAP;
    for (int i = blockIdx.x * 256 + t; i < (int)NC; i += gridDim.x * 256)
        atomicAdd(&h[cand_raw[i] & (FEAT - 1)], 1u);
    __syncthreads();
    for (int i = t; i < 16384; i += 256) {
        unsigned c = h[i];
        if (c) atomicAdd(&fhist[i], c);
    }
}

__global__ __launch_bounds__(1024) void sae20_fscan(const unsigned* __restrict__ fhist,
                                                    unsigned* __restrict__ fofs)
{
    __shared__ unsigned s[1024];
    const int t = threadIdx.x;
    unsigned c[16];
    unsigned sum = 0;
#pragma unroll
    for (int j = 0; j < 16; ++j) { c[j] = fhist[t * 16 + j]; sum += c[j]; }
    s[t] = sum;
    __syncthreads();
    for (int off = 1; off < 1024; off <<= 1) {
        unsigned v = (t >= off) ? s[t - off] : 0u;
        __syncthreads();
        s[t] += v;
        __syncthreads();
    }
    unsigned run = s[t] - sum;
#pragma unroll
    for (int j = 0; j < 16; ++j) { fofs[t * 16 + j] = run; run += c[j]; }
}

__global__ __launch_bounds__(256) void sae20_fscat(const int* __restrict__ cand_raw,
                                                   const unsigned* __restrict__ sl,
                                                   const unsigned* __restrict__ fofs,
                                                   unsigned* __restrict__ fcur,
                                                   int* __restrict__ cand_flat)
{
    unsigned NC = sl[SL_NC];
    if (NC > (unsigned)CCAP) NC = (unsigned)CCAP;
    for (int i = blockIdx.x * 256 + threadIdx.x; i < (int)NC; i += gridDim.x * 256) {
        int flat = cand_raw[i];
        int f = flat & (FEAT - 1);
        unsigned p = atomicAdd(&fcur[f], 1u);
        unsigned dst = fofs[f] + p;
        if (dst < (unsigned)CCAP) cand_flat[dst] = flat;
    }
}

// ===========================================================================
// f64 exact evaluation — FG candidates/wave, reg-cached Wenc row, XCD swizzle
// ===========================================================================
__global__ __launch_bounds__(256) void sae20_feval(const float* __restrict__ x,
                                                   const float* __restrict__ Wenc,
                                                   const float* __restrict__ benc,
                                                   const float* __restrict__ bdec,
                                                   const unsigned* __restrict__ sl,
                                                   const int* __restrict__ cand_flat,
                                                   u64* __restrict__ cand_key)
{
    unsigned NC = sl[SL_NC];
    if (NC > (unsigned)CCAP) NC = (unsigned)CCAP;
    const int lane = threadIdx.x & 63;
    const int b = blockIdx.x;
    const int lb = (b & 7) * (FBLK / 8) + (b >> 3);
    const int wid = lb * 4 + (threadIdx.x >> 6);
    const int c0 = wid * FG;
    if (c0 >= (int)NC) return;

    float bd[12], wv[12];
#pragma unroll
    for (int j = 0; j < 12; ++j) bd[j] = bdec[lane + j * 64];
    int fprev = -1;

    for (int g = 0; g < FG; ++g) {
        const int c = c0 + g;
        if (c >= (int)NC) break;
        const int flat = cand_flat[c];
        const int bb = flat >> 14;
        const int f  = flat & (FEAT - 1);
        if (f != fprev) {
            const float* wr = Wenc + (size_t)f * DIM;
#pragma unroll
            for (int j = 0; j < 12; ++j) wv[j] = wr[lane + j * 64];
            fprev = f;
        }
        const float* xr = x + (size_t)bb * DIM;
        double p = 0.0;
#pragma unroll
        for (int j = 0; j < 12; ++j)
            p = fma((double)xr[lane + j * 64] - (double)bd[j], (double)wv[j], p);
#pragma unroll
        for (int o = 32; o > 0; o >>= 1) p += __shfl_xor(p, o, 64);
        if (lane == 0) {
            p += (double)benc[f];
            if (p < 0.0) p = 0.0;
            cand_key[c] = (u64)__double_as_longlong(p);
        }
    }
}

// ===========================================================================
// u64 radix histogram — 3 LDS-privatized 14-bit passes (42-bit prefix)
// ===========================================================================
__global__ __launch_bounds__(256) void sae20_hist64(const u64* __restrict__ cand_key,
                                                    const unsigned* __restrict__ sl,
                                                    unsigned* __restrict__ hist,
                                                    int pass)
{
    __shared__ unsigned h[16384];
    const int t = threadIdx.x;
    for (int i = t; i < 16384; i += 256) h[i] = 0u;
    __syncthreads();

    unsigned NC = sl[SL_NC];
    if (NC > (unsigned)CCAP) NC = (unsigned)CCAP;
    u64 pref = 0;
    for (int i = 0; i < pass; ++i) pref = (pref << 14) | (u64)sl[SL_S0 + i];
    const int chk_sh = 64 - 14 * pass;
    const int bkt_sh = 50 - 14 * pass;

    for (int i = blockIdx.x * 256 + t; i < (int)NC; i += gridDim.x * 256) {
        u64 key = cand_key[i];
        if (pass > 0 && (key >> chk_sh) != pref) continue;
        atomicAdd(&h[(unsigned)(key >> bkt_sh) & 0x3FFFu], 1u);
    }
    __syncthreads();
    for (int i = t; i < 16384; i += 256) {
        unsigned c = h[i];
        if (c) atomicAdd(&hist[i], c);
    }
}

// ===========================================================================
// 14-bit k-th select per radix pass (rank-K)
// ===========================================================================
__global__ __launch_bounds__(1024) void sae20_sel14(const unsigned* __restrict__ hist,
                                                    unsigned* sl, int pass)
{
    __shared__ unsigned s[1024];
    const int t = threadIdx.x;
    const int C = 16;
    const unsigned N = (pass == 0) ? (unsigned)KB_SEL : sl[SL_S0 + 4 + pass - 1];
    const int lo = t * C;
    unsigned S = 0;
    for (int i = 0; i < C; ++i) S += hist[lo + i];
    s[t] = S;
    __syncthreads();
    for (int off = 1; off < 1024; off <<= 1) {
        unsigned v = (t + off < 1024) ? s[t + off] : 0u;
        __syncthreads();
        s[t] += v;
        __syncthreads();
    }
    const unsigned incl  = s[t];
    const unsigned above = incl - S;
    if (above < N && N <= incl) {
        unsigned cum = above;
        for (int i = lo + C - 1; i >= lo; --i) {
            cum += hist[i];
            if (cum >= N) {
                sl[SL_S0 + pass]     = (unsigned)i;
                sl[SL_S0 + 4 + pass] = N - (cum - hist[i]);
                break;
            }
        }
    }
}

// ===========================================================================
// Max key strictly below rank-K prefix group == rank-(K+1) key
// ===========================================================================
__global__ __launch_bounds__(256) void sae20_maxb(const u64* __restrict__ cand_key,
                                                  const unsigned* __restrict__ sl,
                                                  u64* __restrict__ mx)
{
    unsigned NC = sl[SL_NC];
    if (NC > (unsigned)CCAP) NC = (unsigned)CCAP;
    const u64 Tsh1 = ((u64)sl[SL_S0 + 0] << 28) | ((u64)sl[SL_S0 + 1] << 14) |
                     (u64)sl[SL_S0 + 2];
    u64 m = 0;
    for (int i = blockIdx.x * 256 + threadIdx.x; i < (int)NC; i += gridDim.x * 256) {
        u64 k = cand_key[i];
        if ((k >> 22) < Tsh1 && k > m) m = k;
    }
#pragma unroll
    for (int o = 32; o > 0; o >>= 1) {
        u64 o2 = __shfl_xor(m, o, 64);
        if (o2 > m) m = o2;
    }
    if ((threadIdx.x & 63) == 0 && m) atomicMax((unsigned long long*)mx, m);
}

// ===========================================================================
// Final classify with BOUNDARY SWAP (42-bit prefixes)
// ===========================================================================
__global__ __launch_bounds__(256) void sae20_class(const u64* __restrict__ cand_key,
                                                   const int* __restrict__ cand_flat,
                                                   const u64* __restrict__ mx,
                                                   unsigned* __restrict__ sl,
                                                   unsigned* __restrict__ row_cnt,
                                                   int* __restrict__ sel_flat,
                                                   float* __restrict__ sel_val,
                                                   int* __restrict__ tie_flat,
                                                   u64* __restrict__ tie_key)
{
    unsigned NC = sl[SL_NC];
    if (NC > (unsigned)CCAP) NC = (unsigned)CCAP;
    const u64 Tsh1 = ((u64)sl[SL_S0 + 0] << 28) | ((u64)sl[SL_S0 + 1] << 14) |
                     (u64)sl[SL_S0 + 2];
    const u64 Tsh2 = mx[0] >> 22;
    const int c = blockIdx.x * 256 + threadIdx.x;
    const bool active = (c < (int)NC);
    u64 key = 0;
    int flat = 0;
    u64 keysh = 0;
    if (active) {
        key = cand_key[c];
        keysh = key >> 22;
        flat = cand_flat[c];
    }
    const bool selp = active && (keysh > Tsh1);
    unsigned p = wave_append(&sl[SL_DEF], selp);
    if (selp && p < (unsigned)KB_SEL) {
        sel_flat[p] = flat;
        sel_val[p]  = (float)__longlong_as_double((long long)key);
        atomicAdd(&row_cnt[flat >> 14], 1u);
    }
    const bool tiep = active && !selp && (keysh == Tsh2);
    unsigned q = wave_append(&sl[SL_NTIE], tiep);
    if (tiep && q < (unsigned)TIE_CAP) { tie_flat[q] = flat; tie_key[q] = key; }
}

// ===========================================================================
// Tie/swap resolve: REM lowest flat indices
// ===========================================================================
__global__ __launch_bounds__(256) void sae20_ties(const int* __restrict__ tie_flat,
                                                  const u64* __restrict__ tie_key,
                                                  unsigned* __restrict__ sl,
                                                  int* __restrict__ sel_flat,
                                                  float* __restrict__ sel_val,
                                                  unsigned* __restrict__ row_cnt)
{
    unsigned R = sl[SL_NTIE];
    if (R > (unsigned)TIE_CAP) R = (unsigned)TIE_CAP;
    const unsigned REM = sl[SL_S0 + 6];
    const unsigned D = sl[SL_DEF];
    const int c = blockIdx.x * blockDim.x + threadIdx.x;
    if (c >= (int)R) return;
    const int ic = tie_flat[c];
    unsigned rank = 0;
    for (int j = 0; j < (int)R; ++j)
        if (tie_flat[j] < ic) ++rank;
    if (rank < REM) {
        unsigned p = D + atomicAdd(&sl[SL_WIN], 1u);
        if (p < (unsigned)KB_SEL) {
            sel_flat[p] = ic;
            sel_val[p]  = (float)__longlong_as_double((long long)tie_key[c]);
            atomicAdd(&row_cnt[ic >> 14], 1u);
        }
    }
}

// ===========================================================================
// Row prefix sum
// ===========================================================================
__global__ __launch_bounds__(256) void sae20_scan(const unsigned* __restrict__ row_cnt,
                                                  unsigned* __restrict__ row_ofs)
{
    __shared__ unsigned s[256];
    const int t = threadIdx.x;
    unsigned c[8];
    unsigned sum = 0;
#pragma unroll
    for (int j = 0; j < 8; ++j) { c[j] = row_cnt[t * 8 + j]; sum += c[j]; }
    s[t] = sum;
    __syncthreads();
    for (int off = 1; off < 256; off <<= 1) {
        unsigned v = (t >= off) ? s[t - off] : 0u;
        __syncthreads();
        s[t] += v;
        __syncthreads();
    }
    unsigned run = s[t] - sum;
#pragma unroll
    for (int j = 0; j < 8; ++j) { row_ofs[t * 8 + j] = run; run += c[j]; }
    if (t == 255) row_ofs[2048] = run;
}

// ===========================================================================
// Scatter into row-grouped arrays
// ===========================================================================
__global__ void sae20_scatter(const int* __restrict__ sel_flat,
                              const float* __restrict__ sel_val,
                              const unsigned* __restrict__ row_ofs,
                              unsigned* __restrict__ cursor,
                              int* __restrict__ gf, float* __restrict__ gv)
{
    int e = blockIdx.x * blockDim.x + threadIdx.x;
    if (e >= KB_SEL) return;
    int flat = sel_flat[e];
    int b = flat >> 14;
    unsigned p = atomicAdd(&cursor[b], 1u);
    unsigned dst = row_ofs[b] + p;
    if (dst < (unsigned)KB_SEL) {
        gf[dst] = flat & (FEAT - 1);
        gv[dst] = sel_val[e];
    }
}

// ===========================================================================
// Sparse decode — bf16 Wt, 2-way ILP (even/odd accumulator chains halve the
// serial latency chain; f32 reorder noise ~1e-6 << 0.079 threshold)
// ===========================================================================
__global__ __launch_bounds__(256) void sae20_decode(const int* __restrict__ gf,
                                                    const float* __restrict__ gv,
                                                    const unsigned* __restrict__ row_ofs,
                                                    const unsigned short* __restrict__ Wtb,
                                                    const float* __restrict__ bdec,
                                                    float* __restrict__ out)
{
    const int b = blockIdx.x;
    const int t = threadIdx.x;
    float a0 = 0.f, a1 = 0.f, a2 = 0.f;
    float c0 = 0.f, c1 = 0.f, c2 = 0.f;
    const unsigned s = row_ofs[b];
    const unsigned e = row_ofs[b + 1];
    unsigned i = s;
    for (; i + 1 < e; i += 2) {
        const int f0 = gf[i];
        const int f1 = gf[i + 1];
        const float v0 = gv[i];
        const float v1 = gv[i + 1];
        const unsigned short* w0 = Wtb + (size_t)f0 * DIM;
        const unsigned short* w1 = Wtb + (size_t)f1 * DIM;
        a0 = fmaf(v0, __uint_as_float((unsigned)w0[t]       << 16), a0);
        c0 = fmaf(v1, __uint_as_float((unsigned)w1[t]       << 16), c0);
        a1 = fmaf(v0, __uint_as_float((unsigned)w0[t + 256] << 16), a1);
        c1 = fmaf(v1, __uint_as_float((unsigned)w1[t + 256] << 16), c1);
        a2 = fmaf(v0, __uint_as_float((unsigned)w0[t + 512] << 16), a2);
        c2 = fmaf(v1, __uint_as_float((unsigned)w1[t + 512] << 16), c2);
    }
    if (i < e) {
        const int f0 = gf[i];
        const float v0 = gv[i];
        const unsigned short* w0 = Wtb + (size_t)f0 * DIM;
        a0 = fmaf(v0, __uint_as_float((unsigned)w0[t]       << 16), a0);
        a1 = fmaf(v0, __uint_as_float((unsigned)w0[t + 256] << 16), a1);
        a2 = fmaf(v0, __uint_as_float((unsigned)w0[t + 512] << 16), a2);
    }
    out[(size_t)b * DIM + t]       = (a0 + c0) + bdec[t];
    out[(size_t)b * DIM + t + 256] = (a1 + c1) + bdec[t + 256];
    out[(size_t)b * DIM + t + 512] = (a2 + c2) + bdec[t + 512];
}

// ===========================================================================
extern "C" void kernel_launch(void* const* d_in, const int* in_sizes, int n_in,
                              void* d_out, int out_size, void* d_ws, size_t ws_size,
                              hipStream_t stream)
{
    (void)in_sizes; (void)n_in; (void)out_size;
    const float* x    = (const float*)d_in[0];
    const float* Wenc = (const float*)d_in[1];
    const float* benc = (const float*)d_in[2];
    const float* Wdec = (const float*)d_in[3];
    const float* bdec = (const float*)d_in[4];
    float* out = (float*)d_out;

    char* ws = (char*)d_ws;
    size_t off = 0;
    unsigned short* Wtb = (unsigned short*)(ws + off);     off += (size_t)FEAT * DIM * 2;
    unsigned short* xb  = (unsigned short*)(ws + off);     off += (size_t)BATCH * DIM * 2;
    unsigned short* wb  = (unsigned short*)(ws + off);     off += (size_t)FEAT * DIM * 2;
    u64*      cand_key  = (u64*)(ws + off);                off += (size_t)CCAP * 8;
    int*      cand_raw  = (int*)(ws + off);                off += (size_t)CCAP * 4;
    int*      cand_flat = (int*)(ws + off);                off += (size_t)CCAP * 4;
    int*      tie_flat  = (int*)(ws + off);                off += (size_t)TIE_CAP * 4;
    u64*      tie_key   = (u64*)(ws + off);                off += (size_t)TIE_CAP * 8;
    unsigned* row_ofs   = (unsigned*)(ws + off);           off += 2052 * 4;
    unsigned* fofs      = (unsigned*)(ws + off);           off += 16384 * 4;
    // ---- contiguous ZERO ZONE (single memset) ----
    char* zstart = ws + off;
    int*      sel_flat  = (int*)(ws + off);                off += (size_t)KB_SEL * 4;
    float*    sel_val   = (float*)(ws + off);              off += (size_t)KB_SEL * 4;
    int*      gf        = (int*)(ws + off);                off += (size_t)KB_SEL * 4;
    float*    gv        = (float*)(ws + off);              off += (size_t)KB_SEL * 4;
    unsigned* hist1     = (unsigned*)(ws + off);           off += 8192 * 4;
    unsigned* h64       = (unsigned*)(ws + off);           off += 3 * 16384 * 4;
    unsigned* fhist     = (unsigned*)(ws + off);           off += 16384 * 4;
    unsigned* fcur      = (unsigned*)(ws + off);           off += 16384 * 4;
    unsigned* row_cnt   = (unsigned*)(ws + off);           off += 2048 * 4;
    unsigned* cursor    = (unsigned*)(ws + off);           off += 2048 * 4;
    u64*      mx        = (u64*)(ws + off);                off += 8;
    unsigned* sl        = (unsigned*)(ws + off);           off += 256;
    const size_t zbytes = (size_t)((ws + off) - zstart);
    if (ws_size < off) return;

    hipMemsetAsync(zstart, 0, zbytes, stream);

    // merged pre-convert + decoder transpose
    sae20_prepwt<<<PREP_BLKS + WT_BLKS, 256, 0, stream>>>(x, Wenc, Wdec, bdec, xb, wb, Wtb);

    // sample GEMM (128 rows) -> histogram -> prune threshold (+f32 compare value)
    sae20_sgemm<<<dim3(FEAT / GBN, 1), 256, 0, stream>>>(xb, wb, benc, hist1);
    sae20_selb<<<1, 1024, 0, stream>>>(hist1, sl);

    // main GEMM with inline candidate append (Y never materialized)
    sae20_gemm<<<dim3(FEAT / GBN, BATCH / GBM), 256, 0, stream>>>(xb, wb, benc, sl, cand_raw);

    // feature-major reorder -> exact f64 keys
    sae20_fhist<<<256, 256, 0, stream>>>(cand_raw, sl, fhist);
    sae20_fscan<<<1, 1024, 0, stream>>>(fhist, fofs);
    sae20_fscat<<<256, 256, 0, stream>>>(cand_raw, sl, fofs, fcur, cand_flat);
    sae20_feval<<<FBLK, 256, 0, stream>>>(x, Wenc, benc, bdec, sl, cand_flat, cand_key);

    // rank-K 42-bit prefix (3 passes) + rank-(K+1) via max-below
    for (int p = 0; p < 3; ++p) {
        sae20_hist64<<<256, 256, 0, stream>>>(cand_key, sl, h64 + p * 16384, p);
        sae20_sel14<<<1, 1024, 0, stream>>>(h64 + p * 16384, sl, p);
    }
    sae20_maxb<<<256, 256, 0, stream>>>(cand_key, sl, mx);

    // selection with rank-K <-> rank-(K+1) boundary swap
    sae20_class<<<(CCAP + 255) / 256, 256, 0, stream>>>(cand_key, cand_flat, mx, sl, row_cnt,
                                                        sel_flat, sel_val, tie_flat, tie_key);
    sae20_ties<<<TIE_CAP / 256, 256, 0, stream>>>(tie_flat, tie_key, sl,
                                                  sel_flat, sel_val, row_cnt);

    // group by batch row and decode sparsely (bf16 Wt)
    sae20_scan<<<1, 256, 0, stream>>>(row_cnt, row_ofs);
    sae20_scatter<<<(KB_SEL + 255) / 256, 256, 0, stream>>>(sel_flat, sel_val, row_ofs, cursor, gf, gv);
    sae20_decode<<<BATCH, 256, 0, stream>>>(gf, gv, row_ofs, Wtb, bdec, out);
}